// Round 7
// baseline (412.231 us; speedup 1.0000x reference)
//
#include <hip/hip_runtime.h>
#include <hip/hip_bf16.h>
#include <stdint.h>

#define B_   2
#define S_   2048
#define H_   2048
#define NH_  16
#define HD_  128
#define MTOT (B_*S_)   // 4096

typedef __attribute__((ext_vector_type(8))) short bf16x8;   // 8 bf16 = 4 VGPRs
typedef __attribute__((ext_vector_type(4))) short bf16x4;   // 8B packed store
typedef __attribute__((ext_vector_type(4))) float f32x4;    // MFMA C/D

__device__ __forceinline__ void gload_lds16(const void* g, void* l) {
    __builtin_amdgcn_global_load_lds(
        (const __attribute__((address_space(1))) void*)g,
        (__attribute__((address_space(3))) void*)l, 16, 0, 0);
}

__device__ __forceinline__ unsigned short f2bfu(float x) {
    __hip_bfloat16 h = __float2bfloat16(x);
    return *reinterpret_cast<unsigned short*>(&h);
}
__device__ __forceinline__ int packbf(float a, float b) {
    return (int)f2bfu(a) | ((int)f2bfu(b) << 16);
}

#define BAR()  asm volatile("s_barrier" ::: "memory")
#define WLG0() asm volatile("s_waitcnt lgkmcnt(0)" ::: "memory")
#define WVM(n) asm volatile("s_waitcnt vmcnt(" #n ")" ::: "memory")

// ---------------------------------------------------------------- fused fp32 -> bf16 casts
__global__ void castall(const float* __restrict__ hs,
                        const float* __restrict__ w0, const float* __restrict__ w1,
                        const float* __restrict__ w2, const float* __restrict__ w3,
                        __hip_bfloat16* __restrict__ xb,
                        __hip_bfloat16* __restrict__ o0, __hip_bfloat16* __restrict__ o1,
                        __hip_bfloat16* __restrict__ o2, __hip_bfloat16* __restrict__ o3)
{
    const size_t Q = 1048576;   // float4s per region
    const float* in; __hip_bfloat16* out; size_t base = 0;
    switch (blockIdx.y) {
        case 0:  in = hs; out = xb; break;
        case 1:  in = hs; out = xb; base = Q; break;
        case 2:  in = w0; out = o0; break;
        case 3:  in = w1; out = o1; break;
        case 4:  in = w2; out = o2; break;
        default: in = w3; out = o3; break;
    }
    size_t i = base + (size_t)blockIdx.x * 256 + threadIdx.x;
    float4 v = *(const float4*)(in + i * 4);
    uint2 o;
    o.x = (unsigned)packbf(v.x, v.y);
    o.y = (unsigned)packbf(v.z, v.w);
    *(uint2*)((char*)out + i * 8) = o;
}

// ---------------------------------------------------------------- NT-GEMM body (m97 structure, for gemm_out)
template<int SMEMB, int BF16OUT>
__device__ __forceinline__ void gemm_body(const __hip_bfloat16* __restrict__ Ablk,
                                          const __hip_bfloat16* __restrict__ Wblk,
                                          const float* __restrict__ bias,
                                          void* __restrict__ Cout,
                                          int N, int K, int br, int bc)
{
    __shared__ __align__(16) char smem[SMEMB];
    __hip_bfloat16* As = (__hip_bfloat16*)smem;             // 128x32, 8192 B
    __hip_bfloat16* Bs = (__hip_bfloat16*)(smem + 8192);    // 128x32, 8192 B

    const int tid  = threadIdx.x;
    const int wave = tid >> 6, lane = tid & 63;
    const int quad = lane >> 4, l16 = lane & 15;
    const int wr = wave >> 1, wc = wave & 1;

    f32x4 acc[4][4] = {};

    for (int k0 = 0; k0 < K; k0 += 32) {
#pragma unroll
        for (int t = 0; t < 2; ++t) {
            int c = t * 256 + wave * 64 + lane;
            int row = c >> 2, cc = c & 3;
            int base = (t * 256 + wave * 64) * 16;       // wave-uniform
            gload_lds16(Ablk + (size_t)row * K + k0 + cc * 8, (char*)As + base);
            gload_lds16(Wblk + (size_t)row * K + k0 + cc * 8, (char*)Bs + base);
        }
        __syncthreads();

        bf16x8 af[4], bf[4];
#pragma unroll
        for (int i = 0; i < 4; ++i)
            af[i] = *(const bf16x8*)&As[(wr * 64 + i * 16 + l16) * 32 + quad * 8];
#pragma unroll
        for (int j = 0; j < 4; ++j)
            bf[j] = *(const bf16x8*)&Bs[(wc * 64 + j * 16 + l16) * 32 + quad * 8];

#pragma unroll
        for (int i = 0; i < 4; ++i)
#pragma unroll
            for (int j = 0; j < 4; ++j)
                acc[i][j] = __builtin_amdgcn_mfma_f32_16x16x32_bf16(af[i], bf[j], acc[i][j], 0, 0, 0);
        __syncthreads();
    }

#pragma unroll
    for (int i = 0; i < 4; ++i) {
        int row = br * 128 + wr * 64 + i * 16 + quad * 4;
#pragma unroll
        for (int j = 0; j < 4; ++j) {
            int col = bc * 128 + wc * 64 + j * 16 + l16;
            float bv = bias[col];
#pragma unroll
            for (int r = 0; r < 4; ++r) {
                float v = acc[i][j][r] + bv;
                if (BF16OUT)
                    ((__hip_bfloat16*)Cout)[(size_t)(row + r) * N + col] = __float2bfloat16(v);
                else
                    ((float*)Cout)[(size_t)(row + r) * N + col] = v;
            }
        }
    }
}

// O-projection: fp32 out, 512 blocks (full machine)
__global__ __launch_bounds__(256)
void gemm_out(const __hip_bfloat16* __restrict__ A, const __hip_bfloat16* __restrict__ W,
              const float* __restrict__ bias, float* __restrict__ C)
{
    gemm_body<16384, 0>(A + (size_t)(blockIdx.y * 128) * H_, W + (size_t)(blockIdx.x * 128) * H_,
                        bias, C, H_, H_, blockIdx.y, blockIdx.x);
}

// ---------------------------------------------------------------- 256x128 8-phase GEMM body (qkv)
// BN shrunk 256->128 so grid = 768 = 3 exact rounds of 256 CUs (kills the 1.5-round tail).
// Same 8-phase barrier skeleton / st_16x32 swizzle as the verified 256x256 body; B halves are
// 8KB = 1 load each, so counted waits become WVM(2) (FIFO audit: at each wait point 8 loads
// outstanding, youngest-needed followed by exactly 2 B-loads).
// LDS 96 KiB: A dbuf [0,64K) unchanged | B buf0 [64K,80K) | B buf1 [80K,96K).
template<int EPI>   // 1 = bf16 row-major, 2 = bf16 V^T scatter
__device__ __forceinline__ void gemm256x128_body(const __hip_bfloat16* __restrict__ Xp,
                                                 const __hip_bfloat16* __restrict__ Wp,
                                                 const float* __restrict__ bias,
                                                 void* __restrict__ Cout,
                                                 int bm, int bn, char* smem)
{
    const int tid  = threadIdx.x;
    const int wave = tid >> 6, lane = tid & 63;
    const int quad = lane >> 4, l16 = lane & 15;
    const int wr = wave >> 2, wc = wave & 3;       // 2 x 4 wave grid; per-wave out 128x32

    const int ro = l16 * 64;
    const int co = (((l16 & 8) ? ((quad * 8) ^ 16) : (quad * 8)) << 1);

    // staging decomposition (linear LDS dest -> inverse-swizzled global row/col)
    int r0, c0, r1, c1;
    {
        int D = tid * 16;                          // [0,8K): used by A round 0 AND B (one round)
        int rg = D >> 11, cg = (D >> 10) & 1;
        int rr = (D >> 6) & 15, c = (D & 63) >> 1;
        int cs = (rr & 8) ? (c ^ 16) : c;
        r0 = rg * 16 + rr;  c0 = cg * 32 + cs;
        D = 8192 + tid * 16;                       // [8K,16K): A round 1
        rg = D >> 11; cg = (D >> 10) & 1;
        rr = (D >> 6) & 15; c = (D & 63) >> 1;
        cs = (rr & 8) ? (c ^ 16) : c;
        r1 = rg * 16 + rr;  c1 = cg * 32 + cs;
    }

    char* const A0h = smem + wr * 16384;               // buf0-A, this wave's half
    char* const A1h = smem + 32768 + wr * 16384;       // buf1-A
    char* const B0h = smem + 65536 + (wc >> 1) * 8192; // buf0-B, this wave's half (64 rows)
    char* const B1h = smem + 81920 + (wc >> 1) * 8192; // buf1-B
    const int bsub = (wc & 1) * 2;                     // 2 B-subtiles per wave

    auto STG = [&](char* ldsb, const __hip_bfloat16* g) {      // 16KB A-half: 2 loads
        gload_lds16(g + (size_t)r0 * H_ + c0, ldsb + wave * 1024);
        gload_lds16(g + (size_t)r1 * H_ + c1, ldsb + 8192 + wave * 1024);
    };
    auto STG1 = [&](char* ldsb, const __hip_bfloat16* g) {     // 8KB B-half: 1 load
        gload_lds16(g + (size_t)r0 * H_ + c0, ldsb + wave * 1024);
    };
    auto SRCA = [&](const __hip_bfloat16* P, int t, int hf) {
        return P + (size_t)(hf * 128) * H_ + (size_t)t * 64;
    };
    auto SRCB = [&](const __hip_bfloat16* P, int t, int hf) {
        return P + (size_t)(hf * 64) * H_ + (size_t)t * 64;
    };

    f32x4 acc[8][2] = {};

    // prologue: A(0)->buf0A (4 loads), B(0)->buf0B (2), B(1)->buf1B (2)
    STG (smem,          SRCA(Xp, 0, 0));
    STG (smem + 16384,  SRCA(Xp, 0, 1));
    STG1(smem + 65536,        SRCB(Wp, 0, 0));
    STG1(smem + 65536 + 8192, SRCB(Wp, 0, 1));
    STG1(smem + 81920,        SRCB(Wp, 1, 0));
    STG1(smem + 81920 + 8192, SRCB(Wp, 1, 1));
    WVM(2);                    // retire A(0)+B(0); B(1)x2 in flight
    BAR();

    const int NIT = H_ / 128;  // 16 iterations, 2 K-tiles each
    bf16x8 bfr[2][2];
    for (int j = 0; j < NIT; ++j) {
        const bool more = (j < NIT - 1);
        const int t1 = 2 * j + 1;
#pragma unroll
        for (int ph = 0; ph < 8; ++ph) {
            const int p = ph & 3;
            char* aA = (ph < 4) ? A0h : A1h;
            char* aB = (ph < 4) ? B0h : B1h;

            if (p == 0) {
#pragma unroll
                for (int jj = 0; jj < 2; ++jj)
#pragma unroll
                    for (int kk = 0; kk < 2; ++kk)
                        bfr[jj][kk] = *(const bf16x8*)(aB + ((bsub + jj) * 2 + kk) * 1024 + ro + co);
            }
            bf16x8 af[2][2];
#pragma unroll
            for (int i2 = 0; i2 < 2; ++i2)
#pragma unroll
                for (int kk = 0; kk < 2; ++kk)
                    af[i2][kk] = *(const bf16x8*)(aA + ((2 * p + i2) * 2 + kk) * 1024 + ro + co);

            // stage map: iter j computes tiles 2j (buf0) then 2j+1 (buf1)
            if (ph == 0) { STG(smem + 32768, SRCA(Xp, t1, 0));            // A(2j+1) -> buf1A
                           STG(smem + 49152, SRCA(Xp, t1, 1)); }
            else if (ph == 1 && more) STG1(smem + 65536,        SRCB(Wp, t1 + 1, 0)); // B(2j+2)
            else if (ph == 2 && more) STG1(smem + 65536 + 8192, SRCB(Wp, t1 + 1, 1));
            else if (ph == 4 && more) STG (smem,                SRCA(Xp, t1 + 1, 0)); // A(2j+2)
            else if (ph == 5 && more) STG (smem + 16384,        SRCA(Xp, t1 + 1, 1));
            else if (ph == 6 && more) STG1(smem + 81920,        SRCB(Wp, t1 + 2, 0)); // B(2j+3)
            else if (ph == 7 && more) STG1(smem + 81920 + 8192, SRCB(Wp, t1 + 2, 1));

            if (ph == 3) { if (more) { WVM(2); } else { WVM(0); } }
            if (ph == 7 && more) { WVM(2); }

            BAR();
            WLG0();
            __builtin_amdgcn_sched_barrier(0);
            __builtin_amdgcn_s_setprio(1);
#pragma unroll
            for (int kk = 0; kk < 2; ++kk)
#pragma unroll
                for (int i2 = 0; i2 < 2; ++i2)
#pragma unroll
                    for (int jj = 0; jj < 2; ++jj)
                        acc[2 * p + i2][jj] = __builtin_amdgcn_mfma_f32_16x16x32_bf16(
                            af[i2][kk], bfr[jj][kk], acc[2 * p + i2][jj], 0, 0, 0);
            __builtin_amdgcn_s_setprio(0);
            BAR();
        }
    }

    if (EPI == 2) {
        __hip_bfloat16* VTo = (__hip_bfloat16*)Cout;
#pragma unroll
        for (int i = 0; i < 8; ++i) {
            int tok = bm * 256 + wr * 128 + i * 16 + quad * 4;
            int b = tok >> 11, s = tok & (S_ - 1);
#pragma unroll
            for (int jj = 0; jj < 2; ++jj) {
                int col = bn * 128 + (wc >> 1) * 64 + (wc & 1) * 32 + jj * 16 + l16;
                int h = col >> 7, d = col & 127;
                float bv = bias[col];
                bf16x4 v;
#pragma unroll
                for (int r = 0; r < 4; ++r)
                    v[r] = (short)f2bfu(acc[i][jj][r] + bv);
                *(bf16x4*)(VTo + ((size_t)(b * 16 + h) * 128 + d) * S_ + s) = v;
            }
        }
    } else {
#pragma unroll
        for (int i = 0; i < 8; ++i) {
            int row = bm * 256 + wr * 128 + i * 16 + quad * 4;
#pragma unroll
            for (int jj = 0; jj < 2; ++jj) {
                int col = bn * 128 + (wc >> 1) * 64 + (wc & 1) * 32 + jj * 16 + l16;
                float bv = bias[col];
#pragma unroll
                for (int r = 0; r < 4; ++r)
                    ((__hip_bfloat16*)Cout)[(size_t)(row + r) * H_ + col] =
                        __float2bfloat16(acc[i][jj][r] + bv);
            }
        }
    }
}

// fused QKV: 768 blocks = 3 exact full rounds (zero tail)
__global__ __launch_bounds__(512, 2)
void gemm_qkv8(const __hip_bfloat16* __restrict__ X,
               const __hip_bfloat16* __restrict__ Wq, const __hip_bfloat16* __restrict__ Wk,
               const __hip_bfloat16* __restrict__ Wv,
               const float* __restrict__ bq, const float* __restrict__ bk,
               const float* __restrict__ bv,
               __hip_bfloat16* __restrict__ Qo, __hip_bfloat16* __restrict__ Ko,
               __hip_bfloat16* __restrict__ VTo)
{
    __shared__ __align__(16) char smem[98304];

    const int bid = blockIdx.x;
    const int swz = (bid & 7) * 96 + (bid >> 3);   // bijective (768 % 8 == 0)
    const int sel = swz >> 8;            // 0=Q 1=K 2=V (256 tiles each)
    const int rem = swz & 255;
    const int bm  = rem & 15;            // M tile 0..15
    const int bn  = rem >> 4;            // N tile 0..15 (128-wide)

    const __hip_bfloat16* W = (sel == 0) ? Wq : (sel == 1) ? Wk : Wv;
    const float* bias       = (sel == 0) ? bq : (sel == 1) ? bk : bv;

    const __hip_bfloat16* Xp = X + (size_t)(bm * 256) * H_;
    const __hip_bfloat16* Wp = W + (size_t)(bn * 128) * H_;

    if (sel == 2)
        gemm256x128_body<2>(Xp, Wp, bias, VTo, bm, bn, smem);
    else
        gemm256x128_body<1>(Xp, Wp, bias, (sel == 0) ? Qo : Ko, bm, bn, smem);
}

// ---------------------------------------------------------------- flash attention v7 + T13 defer-max
// softmax tracked in RAW QK^T units; scale folded into fma
__global__ __launch_bounds__(256)
void attn_kernel(const __hip_bfloat16* __restrict__ Q,
                 const __hip_bfloat16* __restrict__ K,
                 const __hip_bfloat16* __restrict__ VT,   // [(b*16+h)*128 + d][s]
                 __hip_bfloat16* __restrict__ O)
{
    __shared__ __align__(16) char Ks[16384];   // K-tile: 64 key-rows x 256B
    __shared__ __align__(16) char Vt[16384];   // V^T-tile: 128 d-rows x 128B

    const int tid  = threadIdx.x;
    const int wave = tid >> 6, lane = tid & 63;
    const int quad = lane >> 4, l16 = lane & 15;

    const int lid = blockIdx.x;
    const int xcd = lid & 7;
    const int q   = lid >> 3;
    const int bh  = ((q >> 5) << 3) | xcd;
    const int qb  = 31 - (q & 31);
    const int b   = bh >> 4, h = bh & 15;

    const size_t headoff = (size_t)b * S_ * H_ + (size_t)h * HD_;
    const __hip_bfloat16* Qp  = Q + headoff;
    const __hip_bfloat16* Kp  = K + headoff;
    const __hip_bfloat16* Vtp = VT + (size_t)(b * 16 + h) * 128 * S_;

    const float scale  = 0.08838834764831843f;    // 1/sqrt(128)
    const float THRraw = 90.50966799187809f;      // 8 / scale
    const int A0 = (((quad & 1) * 2) * 16 + l16) * 4;
    const int A1 = A0 + 64;
    const bool hiq = (quad >= 2);

    const int qrow_local = wave * 16;
    const int qrow = qb * 64 + qrow_local;

    bf16x8 qf[4];
#pragma unroll
    for (int kd = 0; kd < 4; ++kd)
        qf[kd] = *(const bf16x8*)(Qp + (size_t)(qrow + l16) * H_ + kd * 32 + quad * 8);

    f32x4 oacc[8] = {};
    float mi = -1e30f, li = 0.0f;                // mi in RAW units

#pragma unroll
    for (int t = 0; t < 4; ++t) {
        int c = wave * 256 + t * 64 + lane;
        int krow = c >> 4, kpos = c & 15;
        gload_lds16(Kp + (size_t)krow * H_ + (kpos ^ (krow & 7)) * 8,
                    &Ks[(wave * 256 + t * 64) * 16]);
        int vrow = c >> 3, vpos = c & 7;
        gload_lds16(Vtp + (size_t)vrow * S_ + (vpos ^ (vrow & 7)) * 8,
                    &Vt[(wave * 256 + t * 64) * 16]);
    }
    __syncthreads();

    for (int kb = 0; kb <= qb; ++kb) {
        const bool more = (kb < qb);

        f32x4 sacc[4] = {};
#pragma unroll
        for (int cb = 0; cb < 4; ++cb) {
#pragma unroll
            for (int kd = 0; kd < 4; ++kd) {
                int row = cb * 16 + l16;
                int pos = (4 * kd + quad) ^ (l16 & 7);
                bf16x8 kf = *(const bf16x8*)&Ks[row * 256 + pos * 16];
                sacc[cb] = __builtin_amdgcn_mfma_f32_16x16x32_bf16(kf, qf[kd], sacc[cb], 0, 0, 0);
            }
        }

        __syncthreads();

        if (more) {
            const __hip_bfloat16* Kn = Kp + (size_t)(kb + 1) * 64 * H_;
#pragma unroll
            for (int t = 0; t < 4; ++t) {
                int c = wave * 256 + t * 64 + lane;
                int krow = c >> 4, kpos = c & 15;
                gload_lds16(Kn + (size_t)krow * H_ + (kpos ^ (krow & 7)) * 8,
                            &Ks[(wave * 256 + t * 64) * 16]);
            }
        }

        const bool diag = (kb == qb);
        float p[4][4];
        float tm = -1e30f;
#pragma unroll
        for (int cb = 0; cb < 4; ++cb)
#pragma unroll
            for (int r = 0; r < 4; ++r) {
                float s = sacc[cb][r];           // RAW (scale folded into exp below)
                if (diag) {
                    int keyl = cb * 16 + quad * 4 + r;
                    if (keyl > qrow_local + l16) s = -1e30f;
                }
                p[cb][r] = s;
                tm = fmaxf(tm, s);
            }
        tm = fmaxf(tm, __shfl_xor(tm, 16));
        tm = fmaxf(tm, __shfl_xor(tm, 32));

        const bool noresc = __all(tm - mi <= THRraw);
        float mnew = noresc ? mi : fmaxf(mi, tm);
        float ms = mnew * scale;

        float sum = 0.0f;
#pragma unroll
        for (int cb = 0; cb < 4; ++cb)
#pragma unroll
            for (int r = 0; r < 4; ++r) {
                float e = __expf(__builtin_fmaf(p[cb][r], scale, -ms));
                p[cb][r] = e;
                sum += e;
            }
        sum += __shfl_xor(sum, 16);
        sum += __shfl_xor(sum, 32);

        if (noresc) {
            li = li + sum;
        } else {
            float alpha = __expf((mi - mnew) * scale);
            li = li * alpha + sum;
            float ar[4];
#pragma unroll
            for (int r = 0; r < 4; ++r)
                ar[r] = __shfl(alpha, quad * 4 + r);
#pragma unroll
            for (int db = 0; db < 8; ++db)
#pragma unroll
                for (int r = 0; r < 4; ++r)
                    oacc[db][r] *= ar[r];
        }
        mi = mnew;

        int Pp[4][2];
#pragma unroll
        for (int cb = 0; cb < 4; ++cb) {
            Pp[cb][0] = packbf(p[cb][0], p[cb][1]);
            Pp[cb][1] = packbf(p[cb][2], p[cb][3]);
        }
        bf16x8 pf[2];
#pragma unroll
        for (int ks = 0; ks < 2; ++ks) {
            int c0 = 2 * ks, c1 = 2 * ks + 1;
            int d0 = __builtin_amdgcn_ds_bpermute(A0, Pp[c0][0]);
            int e0 = __builtin_amdgcn_ds_bpermute(A0, Pp[c1][0]);
            int d1 = __builtin_amdgcn_ds_bpermute(A0, Pp[c0][1]);
            int e1 = __builtin_amdgcn_ds_bpermute(A0, Pp[c1][1]);
            int d2 = __builtin_amdgcn_ds_bpermute(A1, Pp[c0][0]);
            int e2 = __builtin_amdgcn_ds_bpermute(A1, Pp[c1][0]);
            int d3 = __builtin_amdgcn_ds_bpermute(A1, Pp[c0][1]);
            int e3 = __builtin_amdgcn_ds_bpermute(A1, Pp[c1][1]);
            union { int i[4]; bf16x8 v; } u;
            u.i[0] = hiq ? e0 : d0;
            u.i[1] = hiq ? e1 : d1;
            u.i[2] = hiq ? e2 : d2;
            u.i[3] = hiq ? e3 : d3;
            pf[ks] = u.v;
        }

#pragma unroll
        for (int ks = 0; ks < 2; ++ks) {
#pragma unroll
            for (int db = 0; db < 8; ++db) {
                int vrow = db * 16 + l16;
                int vpos = (ks * 4 + quad) ^ (l16 & 7);
                bf16x8 vf = *(const bf16x8*)&Vt[vrow * 128 + vpos * 16];
                oacc[db] = __builtin_amdgcn_mfma_f32_16x16x32_bf16(pf[ks], vf, oacc[db], 0, 0, 0);
            }
        }

        __syncthreads();

        if (more) {
            const int vcol = (kb + 1) * 64;
#pragma unroll
            for (int t = 0; t < 4; ++t) {
                int c = wave * 256 + t * 64 + lane;
                int vrow = c >> 3, vpos = c & 7;
                gload_lds16(Vtp + (size_t)vrow * S_ + vcol + (vpos ^ (vrow & 7)) * 8,
                            &Vt[(wave * 256 + t * 64) * 16]);
            }
        }
    }

    float lr[4];
#pragma unroll
    for (int r = 0; r < 4; ++r)
        lr[r] = __shfl(li, quad * 4 + r);
#pragma unroll
    for (int db = 0; db < 8; ++db)
#pragma unroll
        for (int r = 0; r < 4; ++r) {
            float v = oacc[db][r] / lr[r];
            size_t row = (size_t)b * S_ + qrow + quad * 4 + r;
            O[row * H_ + h * HD_ + db * 16 + l16] = __float2bfloat16(v);
        }
}

// ---------------------------------------------------------------- launcher
extern "C" void kernel_launch(void* const* d_in, const int* in_sizes, int n_in,
                              void* d_out, int out_size, void* d_ws, size_t ws_size,
                              hipStream_t stream)
{
    const float* hs = (const float*)d_in[0];
    const float* Wq = (const float*)d_in[2];
    const float* bq = (const float*)d_in[3];
    const float* Wk = (const float*)d_in[4];
    const float* bk = (const float*)d_in[5];
    const float* Wv = (const float*)d_in[6];
    const float* bv = (const float*)d_in[7];
    const float* Wo = (const float*)d_in[8];
    const float* bo = (const float*)d_in[9];

    const size_t szX = (size_t)MTOT * H_;
    const size_t szW = (size_t)H_ * H_;

    __hip_bfloat16* Xbf = (__hip_bfloat16*)d_ws;   // reused as attention output
    __hip_bfloat16* Wqb = Xbf + szX;
    __hip_bfloat16* Wkb = Wqb + szW;
    __hip_bfloat16* Wvb = Wkb + szW;
    __hip_bfloat16* Wob = Wvb + szW;
    __hip_bfloat16* Qb  = Wob + szW;
    __hip_bfloat16* Kb  = Qb + szX;
    __hip_bfloat16* VTb = Kb + szX;                // V^T [(b*16+h)*128+d][s]

    castall<<<dim3(4096, 6), 256, 0, stream>>>(hs, Wq, Wk, Wv, Wo, Xbf, Wqb, Wkb, Wvb, Wob);

    gemm_qkv8<<<dim3(768), 512, 0, stream>>>(Xbf, Wqb, Wkb, Wvb, bq, bk, bv, Qb, Kb, VTb);

    attn_kernel<<<dim3(1024), 256, 0, stream>>>(Qb, Kb, VTb, Xbf);

    gemm_out<<<dim3(16, 32), 256, 0, stream>>>(Xbf, Wob, bo, (float*)d_out);
}

// Round 9
// 411.222 us; speedup vs baseline: 1.0025x; 1.0025x over previous
//
#include <hip/hip_runtime.h>
#include <hip/hip_bf16.h>
#include <stdint.h>

#define B_   2
#define S_   2048
#define H_   2048
#define NH_  16
#define HD_  128
#define MTOT (B_*S_)   // 4096

typedef __attribute__((ext_vector_type(8))) short bf16x8;   // 8 bf16 = 4 VGPRs
typedef __attribute__((ext_vector_type(4))) short bf16x4;   // 8B packed store
typedef __attribute__((ext_vector_type(4))) float f32x4;    // MFMA C/D

__device__ __forceinline__ void gload_lds16(const void* g, void* l) {
    __builtin_amdgcn_global_load_lds(
        (const __attribute__((address_space(1))) void*)g,
        (__attribute__((address_space(3))) void*)l, 16, 0, 0);
}

__device__ __forceinline__ unsigned short f2bfu(float x) {
    __hip_bfloat16 h = __float2bfloat16(x);
    return *reinterpret_cast<unsigned short*>(&h);
}
__device__ __forceinline__ int packbf(float a, float b) {
    return (int)f2bfu(a) | ((int)f2bfu(b) << 16);
}

#define BAR()  asm volatile("s_barrier" ::: "memory")
#define WLG0() asm volatile("s_waitcnt lgkmcnt(0)" ::: "memory")
#define WVM(n) asm volatile("s_waitcnt vmcnt(" #n ")" ::: "memory")

// ---------------------------------------------------------------- fused fp32 -> bf16 casts
__global__ void castall(const float* __restrict__ hs,
                        const float* __restrict__ w0, const float* __restrict__ w1,
                        const float* __restrict__ w2, const float* __restrict__ w3,
                        __hip_bfloat16* __restrict__ xb,
                        __hip_bfloat16* __restrict__ o0, __hip_bfloat16* __restrict__ o1,
                        __hip_bfloat16* __restrict__ o2, __hip_bfloat16* __restrict__ o3)
{
    const size_t Q = 1048576;   // float4s per region
    const float* in; __hip_bfloat16* out; size_t base = 0;
    switch (blockIdx.y) {
        case 0:  in = hs; out = xb; break;
        case 1:  in = hs; out = xb; base = Q; break;
        case 2:  in = w0; out = o0; break;
        case 3:  in = w1; out = o1; break;
        case 4:  in = w2; out = o2; break;
        default: in = w3; out = o3; break;
    }
    size_t i = base + (size_t)blockIdx.x * 256 + threadIdx.x;
    float4 v = *(const float4*)(in + i * 4);
    uint2 o;
    o.x = (unsigned)packbf(v.x, v.y);
    o.y = (unsigned)packbf(v.z, v.w);
    *(uint2*)((char*)out + i * 8) = o;
}

// ---------------------------------------------------------------- NT-GEMM body (m97 structure, for gemm_out)
template<int SMEMB, int BF16OUT>
__device__ __forceinline__ void gemm_body(const __hip_bfloat16* __restrict__ Ablk,
                                          const __hip_bfloat16* __restrict__ Wblk,
                                          const float* __restrict__ bias,
                                          void* __restrict__ Cout,
                                          int N, int K, int br, int bc)
{
    __shared__ __align__(16) char smem[SMEMB];
    __hip_bfloat16* As = (__hip_bfloat16*)smem;             // 128x32, 8192 B
    __hip_bfloat16* Bs = (__hip_bfloat16*)(smem + 8192);    // 128x32, 8192 B

    const int tid  = threadIdx.x;
    const int wave = tid >> 6, lane = tid & 63;
    const int quad = lane >> 4, l16 = lane & 15;
    const int wr = wave >> 1, wc = wave & 1;

    f32x4 acc[4][4] = {};

    for (int k0 = 0; k0 < K; k0 += 32) {
#pragma unroll
        for (int t = 0; t < 2; ++t) {
            int c = t * 256 + wave * 64 + lane;
            int row = c >> 2, cc = c & 3;
            int base = (t * 256 + wave * 64) * 16;       // wave-uniform
            gload_lds16(Ablk + (size_t)row * K + k0 + cc * 8, (char*)As + base);
            gload_lds16(Wblk + (size_t)row * K + k0 + cc * 8, (char*)Bs + base);
        }
        __syncthreads();

        bf16x8 af[4], bf[4];
#pragma unroll
        for (int i = 0; i < 4; ++i)
            af[i] = *(const bf16x8*)&As[(wr * 64 + i * 16 + l16) * 32 + quad * 8];
#pragma unroll
        for (int j = 0; j < 4; ++j)
            bf[j] = *(const bf16x8*)&Bs[(wc * 64 + j * 16 + l16) * 32 + quad * 8];

#pragma unroll
        for (int i = 0; i < 4; ++i)
#pragma unroll
            for (int j = 0; j < 4; ++j)
                acc[i][j] = __builtin_amdgcn_mfma_f32_16x16x32_bf16(af[i], bf[j], acc[i][j], 0, 0, 0);
        __syncthreads();
    }

#pragma unroll
    for (int i = 0; i < 4; ++i) {
        int row = br * 128 + wr * 64 + i * 16 + quad * 4;
#pragma unroll
        for (int j = 0; j < 4; ++j) {
            int col = bc * 128 + wc * 64 + j * 16 + l16;
            float bv = bias[col];
#pragma unroll
            for (int r = 0; r < 4; ++r) {
                float v = acc[i][j][r] + bv;
                if (BF16OUT)
                    ((__hip_bfloat16*)Cout)[(size_t)(row + r) * N + col] = __float2bfloat16(v);
                else
                    ((float*)Cout)[(size_t)(row + r) * N + col] = v;
            }
        }
    }
}

// O-projection: fp32 out, 512 blocks (full machine)
__global__ __launch_bounds__(256)
void gemm_out(const __hip_bfloat16* __restrict__ A, const __hip_bfloat16* __restrict__ W,
              const float* __restrict__ bias, float* __restrict__ C)
{
    gemm_body<16384, 0>(A + (size_t)(blockIdx.y * 128) * H_, W + (size_t)(blockIdx.x * 128) * H_,
                        bias, C, H_, H_, blockIdx.y, blockIdx.x);
}

// ---------------------------------------------------------------- 256x128 8-phase GEMM body (qkv)
// 768 blocks = 3 exact rounds. Round-7 counters: tail gone (Occ 20.6) but FETCH 144->209MB
// from bm-fastest ordering (resident set spanned all 16 A-panels). This round: bn-fastest.
template<int EPI>   // 1 = bf16 row-major, 2 = bf16 V^T scatter
__device__ __forceinline__ void gemm256x128_body(const __hip_bfloat16* __restrict__ Xp,
                                                 const __hip_bfloat16* __restrict__ Wp,
                                                 const float* __restrict__ bias,
                                                 void* __restrict__ Cout,
                                                 int bm, int bn, char* smem)
{
    const int tid  = threadIdx.x;
    const int wave = tid >> 6, lane = tid & 63;
    const int quad = lane >> 4, l16 = lane & 15;
    const int wr = wave >> 2, wc = wave & 3;       // 2 x 4 wave grid; per-wave out 128x32

    const int ro = l16 * 64;
    const int co = (((l16 & 8) ? ((quad * 8) ^ 16) : (quad * 8)) << 1);

    int r0, c0, r1, c1;
    {
        int D = tid * 16;
        int rg = D >> 11, cg = (D >> 10) & 1;
        int rr = (D >> 6) & 15, c = (D & 63) >> 1;
        int cs = (rr & 8) ? (c ^ 16) : c;
        r0 = rg * 16 + rr;  c0 = cg * 32 + cs;
        D = 8192 + tid * 16;
        rg = D >> 11; cg = (D >> 10) & 1;
        rr = (D >> 6) & 15; c = (D & 63) >> 1;
        cs = (rr & 8) ? (c ^ 16) : c;
        r1 = rg * 16 + rr;  c1 = cg * 32 + cs;
    }

    char* const A0h = smem + wr * 16384;
    char* const A1h = smem + 32768 + wr * 16384;
    char* const B0h = smem + 65536 + (wc >> 1) * 8192;
    char* const B1h = smem + 81920 + (wc >> 1) * 8192;
    const int bsub = (wc & 1) * 2;

    auto STG = [&](char* ldsb, const __hip_bfloat16* g) {
        gload_lds16(g + (size_t)r0 * H_ + c0, ldsb + wave * 1024);
        gload_lds16(g + (size_t)r1 * H_ + c1, ldsb + 8192 + wave * 1024);
    };
    auto STG1 = [&](char* ldsb, const __hip_bfloat16* g) {
        gload_lds16(g + (size_t)r0 * H_ + c0, ldsb + wave * 1024);
    };
    auto SRCA = [&](const __hip_bfloat16* P, int t, int hf) {
        return P + (size_t)(hf * 128) * H_ + (size_t)t * 64;
    };
    auto SRCB = [&](const __hip_bfloat16* P, int t, int hf) {
        return P + (size_t)(hf * 64) * H_ + (size_t)t * 64;
    };

    f32x4 acc[8][2] = {};

    STG (smem,          SRCA(Xp, 0, 0));
    STG (smem + 16384,  SRCA(Xp, 0, 1));
    STG1(smem + 65536,        SRCB(Wp, 0, 0));
    STG1(smem + 65536 + 8192, SRCB(Wp, 0, 1));
    STG1(smem + 81920,        SRCB(Wp, 1, 0));
    STG1(smem + 81920 + 8192, SRCB(Wp, 1, 1));
    WVM(2);
    BAR();

    const int NIT = H_ / 128;  // 16 iterations, 2 K-tiles each
    bf16x8 bfr[2][2];
    for (int j = 0; j < NIT; ++j) {
        const bool more = (j < NIT - 1);
        const int t1 = 2 * j + 1;
#pragma unroll
        for (int ph = 0; ph < 8; ++ph) {
            const int p = ph & 3;
            char* aA = (ph < 4) ? A0h : A1h;
            char* aB = (ph < 4) ? B0h : B1h;

            if (p == 0) {
#pragma unroll
                for (int jj = 0; jj < 2; ++jj)
#pragma unroll
                    for (int kk = 0; kk < 2; ++kk)
                        bfr[jj][kk] = *(const bf16x8*)(aB + ((bsub + jj) * 2 + kk) * 1024 + ro + co);
            }
            bf16x8 af[2][2];
#pragma unroll
            for (int i2 = 0; i2 < 2; ++i2)
#pragma unroll
                for (int kk = 0; kk < 2; ++kk)
                    af[i2][kk] = *(const bf16x8*)(aA + ((2 * p + i2) * 2 + kk) * 1024 + ro + co);

            if (ph == 0) { STG(smem + 32768, SRCA(Xp, t1, 0));
                           STG(smem + 49152, SRCA(Xp, t1, 1)); }
            else if (ph == 1 && more) STG1(smem + 65536,        SRCB(Wp, t1 + 1, 0));
            else if (ph == 2 && more) STG1(smem + 65536 + 8192, SRCB(Wp, t1 + 1, 1));
            else if (ph == 4 && more) STG (smem,                SRCA(Xp, t1 + 1, 0));
            else if (ph == 5 && more) STG (smem + 16384,        SRCA(Xp, t1 + 1, 1));
            else if (ph == 6 && more) STG1(smem + 81920,        SRCB(Wp, t1 + 2, 0));
            else if (ph == 7 && more) STG1(smem + 81920 + 8192, SRCB(Wp, t1 + 2, 1));

            if (ph == 3) { if (more) { WVM(2); } else { WVM(0); } }
            if (ph == 7 && more) { WVM(2); }

            BAR();
            WLG0();
            __builtin_amdgcn_sched_barrier(0);
            __builtin_amdgcn_s_setprio(1);
#pragma unroll
            for (int kk = 0; kk < 2; ++kk)
#pragma unroll
                for (int i2 = 0; i2 < 2; ++i2)
#pragma unroll
                    for (int jj = 0; jj < 2; ++jj)
                        acc[2 * p + i2][jj] = __builtin_amdgcn_mfma_f32_16x16x32_bf16(
                            af[i2][kk], bfr[jj][kk], acc[2 * p + i2][jj], 0, 0, 0);
            __builtin_amdgcn_s_setprio(0);
            BAR();
        }
    }

    if (EPI == 2) {
        __hip_bfloat16* VTo = (__hip_bfloat16*)Cout;
#pragma unroll
        for (int i = 0; i < 8; ++i) {
            int tok = bm * 256 + wr * 128 + i * 16 + quad * 4;
            int b = tok >> 11, s = tok & (S_ - 1);
#pragma unroll
            for (int jj = 0; jj < 2; ++jj) {
                int col = bn * 128 + (wc >> 1) * 64 + (wc & 1) * 32 + jj * 16 + l16;
                int h = col >> 7, d = col & 127;
                float bv = bias[col];
                bf16x4 v;
#pragma unroll
                for (int r = 0; r < 4; ++r)
                    v[r] = (short)f2bfu(acc[i][jj][r] + bv);
                *(bf16x4*)(VTo + ((size_t)(b * 16 + h) * 128 + d) * S_ + s) = v;
            }
        }
    } else {
#pragma unroll
        for (int i = 0; i < 8; ++i) {
            int row = bm * 256 + wr * 128 + i * 16 + quad * 4;
#pragma unroll
            for (int jj = 0; jj < 2; ++jj) {
                int col = bn * 128 + (wc >> 1) * 64 + (wc & 1) * 32 + jj * 16 + l16;
                float bv = bias[col];
#pragma unroll
                for (int r = 0; r < 4; ++r)
                    ((__hip_bfloat16*)Cout)[(size_t)(row + r) * H_ + col] =
                        __float2bfloat16(acc[i][jj][r] + bv);
            }
        }
    }
}

// fused QKV: 768 blocks = 3 exact rounds; bn-FASTEST swizzle for A-panel L2 reuse
__global__ __launch_bounds__(512, 2)
void gemm_qkv8(const __hip_bfloat16* __restrict__ X,
               const __hip_bfloat16* __restrict__ Wq, const __hip_bfloat16* __restrict__ Wk,
               const __hip_bfloat16* __restrict__ Wv,
               const float* __restrict__ bq, const float* __restrict__ bk,
               const float* __restrict__ bv,
               __hip_bfloat16* __restrict__ Qo, __hip_bfloat16* __restrict__ Ko,
               __hip_bfloat16* __restrict__ VTo)
{
    __shared__ __align__(16) char smem[98304];

    const int bid = blockIdx.x;
    const int swz = (bid & 7) * 96 + (bid >> 3);   // bijective (768 % 8 == 0)
    const int sel = swz >> 8;            // 0=Q 1=K 2=V (256 tiles each)
    const int rem = swz & 255;
    const int bn  = rem & 15;            // N tile fastest: resident set = ~2 A-panels x 16 B-panels
    const int bm  = rem >> 4;            // M tile

    const __hip_bfloat16* W = (sel == 0) ? Wq : (sel == 1) ? Wk : Wv;
    const float* bias       = (sel == 0) ? bq : (sel == 1) ? bk : bv;

    const __hip_bfloat16* Xp = X + (size_t)(bm * 256) * H_;
    const __hip_bfloat16* Wp = W + (size_t)(bn * 128) * H_;

    if (sel == 2)
        gemm256x128_body<2>(Xp, Wp, bias, VTo, bm, bn, smem);
    else
        gemm256x128_body<1>(Xp, Wp, bias, (sel == 0) ? Qo : Ko, bm, bn, smem);
}

// ---------------------------------------------------------------- flash attention v8
// K/V double-buffered (64 KiB), issue-early / drain-late: prefetch tile kb+1 at iter TOP,
// single __syncthreads per iter at the BOTTOM -> DMA latency covered by a full iteration
// (QK + softmax + PV) instead of one MFMA cluster. Hazards: prefetch writes buf cur^1
// (readers passed previous barrier); QK/PV read buf cur (DMA drained by previous barrier).
__global__ __launch_bounds__(256)
void attn_kernel(const __hip_bfloat16* __restrict__ Q,
                 const __hip_bfloat16* __restrict__ K,
                 const __hip_bfloat16* __restrict__ VT,   // [(b*16+h)*128 + d][s]
                 __hip_bfloat16* __restrict__ O)
{
    __shared__ __align__(16) char Ks[2][16384];   // K-tile: 64 key-rows x 256B
    __shared__ __align__(16) char Vt[2][16384];   // V^T-tile: 128 d-rows x 128B

    const int tid  = threadIdx.x;
    const int wave = tid >> 6, lane = tid & 63;
    const int quad = lane >> 4, l16 = lane & 15;

    const int lid = blockIdx.x;
    const int xcd = lid & 7;
    const int q   = lid >> 3;
    const int bh  = ((q >> 5) << 3) | xcd;
    const int qb  = 31 - (q & 31);               // LPT: heavy q-tiles first
    const int b   = bh >> 4, h = bh & 15;

    const size_t headoff = (size_t)b * S_ * H_ + (size_t)h * HD_;
    const __hip_bfloat16* Qp  = Q + headoff;
    const __hip_bfloat16* Kp  = K + headoff;
    const __hip_bfloat16* Vtp = VT + (size_t)(b * 16 + h) * 128 * S_;

    const float scale  = 0.08838834764831843f;    // 1/sqrt(128)
    const float THRraw = 90.50966799187809f;      // 8 / scale
    const int A0 = (((quad & 1) * 2) * 16 + l16) * 4;
    const int A1 = A0 + 64;
    const bool hiq = (quad >= 2);

    const int qrow_local = wave * 16;
    const int qrow = qb * 64 + qrow_local;

    bf16x8 qf[4];
#pragma unroll
    for (int kd = 0; kd < 4; ++kd)
        qf[kd] = *(const bf16x8*)(Qp + (size_t)(qrow + l16) * H_ + kd * 32 + quad * 8);

    f32x4 oacc[8] = {};
    float mi = -1e30f, li = 0.0f;                // mi in RAW units

    // prologue: tile 0 -> buf 0
#pragma unroll
    for (int t = 0; t < 4; ++t) {
        int c = wave * 256 + t * 64 + lane;
        int krow = c >> 4, kpos = c & 15;
        gload_lds16(Kp + (size_t)krow * H_ + (kpos ^ (krow & 7)) * 8,
                    &Ks[0][(wave * 256 + t * 64) * 16]);
        int vrow = c >> 3, vpos = c & 7;
        gload_lds16(Vtp + (size_t)vrow * S_ + (vpos ^ (vrow & 7)) * 8,
                    &Vt[0][(wave * 256 + t * 64) * 16]);
    }
    __syncthreads();   // drains DMA -> tile 0 ready

    for (int kb = 0; kb <= qb; ++kb) {
        const int cur = kb & 1;
        const bool more = (kb < qb);

        // prefetch tile kb+1 into the other buffer (issued BEFORE compute; drained at
        // this iter's bottom barrier, a full QK+softmax+PV later)
        if (more) {
            const __hip_bfloat16* Kn = Kp + (size_t)(kb + 1) * 64 * H_;
            const int vcol = (kb + 1) * 64;
#pragma unroll
            for (int t = 0; t < 4; ++t) {
                int c = wave * 256 + t * 64 + lane;
                int krow = c >> 4, kpos = c & 15;
                gload_lds16(Kn + (size_t)krow * H_ + (kpos ^ (krow & 7)) * 8,
                            &Ks[cur ^ 1][(wave * 256 + t * 64) * 16]);
                int vrow = c >> 3, vpos = c & 7;
                gload_lds16(Vtp + (size_t)vrow * S_ + vcol + (vpos ^ (vrow & 7)) * 8,
                            &Vt[cur ^ 1][(wave * 256 + t * 64) * 16]);
            }
        }

        // ---- S^T tile: D[key][query] = K.Q^T
        f32x4 sacc[4] = {};
#pragma unroll
        for (int cb = 0; cb < 4; ++cb) {
#pragma unroll
            for (int kd = 0; kd < 4; ++kd) {
                int row = cb * 16 + l16;
                int pos = (4 * kd + quad) ^ (l16 & 7);
                bf16x8 kf = *(const bf16x8*)&Ks[cur][row * 256 + pos * 16];
                sacc[cb] = __builtin_amdgcn_mfma_f32_16x16x32_bf16(kf, qf[kd], sacc[cb], 0, 0, 0);
            }
        }

        const bool diag = (kb == qb);
        float p[4][4];
        float tm = -1e30f;
#pragma unroll
        for (int cb = 0; cb < 4; ++cb)
#pragma unroll
            for (int r = 0; r < 4; ++r) {
                float s = sacc[cb][r];           // RAW (scale folded into exp)
                if (diag) {
                    int keyl = cb * 16 + quad * 4 + r;
                    if (keyl > qrow_local + l16) s = -1e30f;
                }
                p[cb][r] = s;
                tm = fmaxf(tm, s);
            }
        tm = fmaxf(tm, __shfl_xor(tm, 16));
        tm = fmaxf(tm, __shfl_xor(tm, 32));

        const bool noresc = __all(tm - mi <= THRraw);
        float mnew = noresc ? mi : fmaxf(mi, tm);
        float ms = mnew * scale;

        float sum = 0.0f;
#pragma unroll
        for (int cb = 0; cb < 4; ++cb)
#pragma unroll
            for (int r = 0; r < 4; ++r) {
                float e = __expf(__builtin_fmaf(p[cb][r], scale, -ms));
                p[cb][r] = e;
                sum += e;
            }
        sum += __shfl_xor(sum, 16);
        sum += __shfl_xor(sum, 32);

        if (noresc) {
            li = li + sum;
        } else {
            float alpha = __expf((mi - mnew) * scale);
            li = li * alpha + sum;
            float ar[4];
#pragma unroll
            for (int r = 0; r < 4; ++r)
                ar[r] = __shfl(alpha, quad * 4 + r);
#pragma unroll
            for (int db = 0; db < 8; ++db)
#pragma unroll
                for (int r = 0; r < 4; ++r)
                    oacc[db][r] *= ar[r];
        }
        mi = mnew;

        int Pp[4][2];
#pragma unroll
        for (int cb = 0; cb < 4; ++cb) {
            Pp[cb][0] = packbf(p[cb][0], p[cb][1]);
            Pp[cb][1] = packbf(p[cb][2], p[cb][3]);
        }
        bf16x8 pf[2];
#pragma unroll
        for (int ks = 0; ks < 2; ++ks) {
            int c0 = 2 * ks, c1 = 2 * ks + 1;
            int d0 = __builtin_amdgcn_ds_bpermute(A0, Pp[c0][0]);
            int e0 = __builtin_amdgcn_ds_bpermute(A0, Pp[c1][0]);
            int d1 = __builtin_amdgcn_ds_bpermute(A0, Pp[c0][1]);
            int e1 = __builtin_amdgcn_ds_bpermute(A0, Pp[c1][1]);
            int d2 = __builtin_amdgcn_ds_bpermute(A1, Pp[c0][0]);
            int e2 = __builtin_amdgcn_ds_bpermute(A1, Pp[c1][0]);
            int d3 = __builtin_amdgcn_ds_bpermute(A1, Pp[c0][1]);
            int e3 = __builtin_amdgcn_ds_bpermute(A1, Pp[c1][1]);
            union { int i[4]; bf16x8 v; } u;
            u.i[0] = hiq ? e0 : d0;
            u.i[1] = hiq ? e1 : d1;
            u.i[2] = hiq ? e2 : d2;
            u.i[3] = hiq ? e3 : d3;
            pf[ks] = u.v;
        }

#pragma unroll
        for (int ks = 0; ks < 2; ++ks) {
#pragma unroll
            for (int db = 0; db < 8; ++db) {
                int vrow = db * 16 + l16;
                int vpos = (ks * 4 + quad) ^ (l16 & 7);
                bf16x8 vf = *(const bf16x8*)&Vt[cur][vrow * 128 + vpos * 16];
                oacc[db] = __builtin_amdgcn_mfma_f32_16x16x32_bf16(pf[ks], vf, oacc[db], 0, 0, 0);
            }
        }

        __syncthreads();   // all reads of buf cur done + prefetch DMA landed
    }

    float lr[4];
#pragma unroll
    for (int r = 0; r < 4; ++r)
        lr[r] = __shfl(li, quad * 4 + r);
#pragma unroll
    for (int db = 0; db < 8; ++db)
#pragma unroll
        for (int r = 0; r < 4; ++r) {
            float v = oacc[db][r] / lr[r];
            size_t row = (size_t)b * S_ + qrow + quad * 4 + r;
            O[row * H_ + h * HD_ + db * 16 + l16] = __float2bfloat16(v);
        }
}

// ---------------------------------------------------------------- launcher
extern "C" void kernel_launch(void* const* d_in, const int* in_sizes, int n_in,
                              void* d_out, int out_size, void* d_ws, size_t ws_size,
                              hipStream_t stream)
{
    const float* hs = (const float*)d_in[0];
    const float* Wq = (const float*)d_in[2];
    const float* bq = (const float*)d_in[3];
    const float* Wk = (const float*)d_in[4];
    const float* bk = (const float*)d_in[5];
    const float* Wv = (const float*)d_in[6];
    const float* bv = (const float*)d_in[7];
    const float* Wo = (const float*)d_in[8];
    const float* bo = (const float*)d_in[9];

    const size_t szX = (size_t)MTOT * H_;
    const size_t szW = (size_t)H_ * H_;

    __hip_bfloat16* Xbf = (__hip_bfloat16*)d_ws;   // reused as attention output
    __hip_bfloat16* Wqb = Xbf + szX;
    __hip_bfloat16* Wkb = Wqb + szW;
    __hip_bfloat16* Wvb = Wkb + szW;
    __hip_bfloat16* Wob = Wvb + szW;
    __hip_bfloat16* Qb  = Wob + szW;
    __hip_bfloat16* Kb  = Qb + szX;
    __hip_bfloat16* VTb = Kb + szX;                // V^T [(b*16+h)*128+d][s]

    castall<<<dim3(4096, 6), 256, 0, stream>>>(hs, Wq, Wk, Wv, Wo, Xbf, Wqb, Wkb, Wvb, Wob);

    gemm_qkv8<<<dim3(768), 512, 0, stream>>>(Xbf, Wqb, Wkb, Wvb, bq, bk, bv, Qb, Kb, VTb);

    attn_kernel<<<dim3(1024), 256, 0, stream>>>(Qb, Kb, VTb, Xbf);

    gemm_out<<<dim3(16, 32), 256, 0, stream>>>(Xbf, Wob, bo, (float*)d_out);
}

// Round 10
// 390.670 us; speedup vs baseline: 1.0552x; 1.0526x over previous
//
#include <hip/hip_runtime.h>
#include <hip/hip_bf16.h>
#include <stdint.h>

#define B_   2
#define S_   2048
#define H_   2048
#define NH_  16
#define HD_  128
#define MTOT (B_*S_)   // 4096

typedef __attribute__((ext_vector_type(8))) short bf16x8;   // 8 bf16 = 4 VGPRs
typedef __attribute__((ext_vector_type(4))) short bf16x4;   // 8B packed store
typedef __attribute__((ext_vector_type(4))) float f32x4;    // MFMA C/D

__device__ __forceinline__ void gload_lds16(const void* g, void* l) {
    __builtin_amdgcn_global_load_lds(
        (const __attribute__((address_space(1))) void*)g,
        (__attribute__((address_space(3))) void*)l, 16, 0, 0);
}

__device__ __forceinline__ unsigned short f2bfu(float x) {
    __hip_bfloat16 h = __float2bfloat16(x);
    return *reinterpret_cast<unsigned short*>(&h);
}
__device__ __forceinline__ int packbf(float a, float b) {
    return (int)f2bfu(a) | ((int)f2bfu(b) << 16);
}

#define BAR()  asm volatile("s_barrier" ::: "memory")
#define WLG0() asm volatile("s_waitcnt lgkmcnt(0)" ::: "memory")
#define WVM(n) asm volatile("s_waitcnt vmcnt(" #n ")" ::: "memory")

// ---------------------------------------------------------------- fused fp32 -> bf16 casts
__global__ void castall(const float* __restrict__ hs,
                        const float* __restrict__ w0, const float* __restrict__ w1,
                        const float* __restrict__ w2, const float* __restrict__ w3,
                        __hip_bfloat16* __restrict__ xb,
                        __hip_bfloat16* __restrict__ o0, __hip_bfloat16* __restrict__ o1,
                        __hip_bfloat16* __restrict__ o2, __hip_bfloat16* __restrict__ o3)
{
    const size_t Q = 1048576;   // float4s per region
    const float* in; __hip_bfloat16* out; size_t base = 0;
    switch (blockIdx.y) {
        case 0:  in = hs; out = xb; break;
        case 1:  in = hs; out = xb; base = Q; break;
        case 2:  in = w0; out = o0; break;
        case 3:  in = w1; out = o1; break;
        case 4:  in = w2; out = o2; break;
        default: in = w3; out = o3; break;
    }
    size_t i = base + (size_t)blockIdx.x * 256 + threadIdx.x;
    float4 v = *(const float4*)(in + i * 4);
    uint2 o;
    o.x = (unsigned)packbf(v.x, v.y);
    o.y = (unsigned)packbf(v.z, v.w);
    *(uint2*)((char*)out + i * 8) = o;
}

// ---------------------------------------------------------------- NT-GEMM body (m97 structure, for gemm_out)
template<int SMEMB, int BF16OUT>
__device__ __forceinline__ void gemm_body(const __hip_bfloat16* __restrict__ Ablk,
                                          const __hip_bfloat16* __restrict__ Wblk,
                                          const float* __restrict__ bias,
                                          void* __restrict__ Cout,
                                          int N, int K, int br, int bc)
{
    __shared__ __align__(16) char smem[SMEMB];
    __hip_bfloat16* As = (__hip_bfloat16*)smem;             // 128x32, 8192 B
    __hip_bfloat16* Bs = (__hip_bfloat16*)(smem + 8192);    // 128x32, 8192 B

    const int tid  = threadIdx.x;
    const int wave = tid >> 6, lane = tid & 63;
    const int quad = lane >> 4, l16 = lane & 15;
    const int wr = wave >> 1, wc = wave & 1;

    f32x4 acc[4][4] = {};

    for (int k0 = 0; k0 < K; k0 += 32) {
#pragma unroll
        for (int t = 0; t < 2; ++t) {
            int c = t * 256 + wave * 64 + lane;
            int row = c >> 2, cc = c & 3;
            int base = (t * 256 + wave * 64) * 16;       // wave-uniform
            gload_lds16(Ablk + (size_t)row * K + k0 + cc * 8, (char*)As + base);
            gload_lds16(Wblk + (size_t)row * K + k0 + cc * 8, (char*)Bs + base);
        }
        __syncthreads();

        bf16x8 af[4], bf[4];
#pragma unroll
        for (int i = 0; i < 4; ++i)
            af[i] = *(const bf16x8*)&As[(wr * 64 + i * 16 + l16) * 32 + quad * 8];
#pragma unroll
        for (int j = 0; j < 4; ++j)
            bf[j] = *(const bf16x8*)&Bs[(wc * 64 + j * 16 + l16) * 32 + quad * 8];

#pragma unroll
        for (int i = 0; i < 4; ++i)
#pragma unroll
            for (int j = 0; j < 4; ++j)
                acc[i][j] = __builtin_amdgcn_mfma_f32_16x16x32_bf16(af[i], bf[j], acc[i][j], 0, 0, 0);
        __syncthreads();
    }

#pragma unroll
    for (int i = 0; i < 4; ++i) {
        int row = br * 128 + wr * 64 + i * 16 + quad * 4;
#pragma unroll
        for (int j = 0; j < 4; ++j) {
            int col = bc * 128 + wc * 64 + j * 16 + l16;
            float bv = bias[col];
#pragma unroll
            for (int r = 0; r < 4; ++r) {
                float v = acc[i][j][r] + bv;
                if (BF16OUT)
                    ((__hip_bfloat16*)Cout)[(size_t)(row + r) * N + col] = __float2bfloat16(v);
                else
                    ((float*)Cout)[(size_t)(row + r) * N + col] = v;
            }
        }
    }
}

// O-projection: fp32 out, 512 blocks (full machine)
__global__ __launch_bounds__(256)
void gemm_out(const __hip_bfloat16* __restrict__ A, const __hip_bfloat16* __restrict__ W,
              const float* __restrict__ bias, float* __restrict__ C)
{
    gemm_body<16384, 0>(A + (size_t)(blockIdx.y * 128) * H_, W + (size_t)(blockIdx.x * 128) * H_,
                        bias, C, H_, H_, blockIdx.y, blockIdx.x);
}

// ---------------------------------------------------------------- 256x128 8-phase GEMM body (qkv)
// 768 blocks = 3 exact rounds; bn-fastest swizzle verified round 9: FETCH 209->123 MB, 119.4 us.
template<int EPI>   // 1 = bf16 row-major, 2 = bf16 V^T scatter
__device__ __forceinline__ void gemm256x128_body(const __hip_bfloat16* __restrict__ Xp,
                                                 const __hip_bfloat16* __restrict__ Wp,
                                                 const float* __restrict__ bias,
                                                 void* __restrict__ Cout,
                                                 int bm, int bn, char* smem)
{
    const int tid  = threadIdx.x;
    const int wave = tid >> 6, lane = tid & 63;
    const int quad = lane >> 4, l16 = lane & 15;
    const int wr = wave >> 2, wc = wave & 3;       // 2 x 4 wave grid; per-wave out 128x32

    const int ro = l16 * 64;
    const int co = (((l16 & 8) ? ((quad * 8) ^ 16) : (quad * 8)) << 1);

    int r0, c0, r1, c1;
    {
        int D = tid * 16;
        int rg = D >> 11, cg = (D >> 10) & 1;
        int rr = (D >> 6) & 15, c = (D & 63) >> 1;
        int cs = (rr & 8) ? (c ^ 16) : c;
        r0 = rg * 16 + rr;  c0 = cg * 32 + cs;
        D = 8192 + tid * 16;
        rg = D >> 11; cg = (D >> 10) & 1;
        rr = (D >> 6) & 15; c = (D & 63) >> 1;
        cs = (rr & 8) ? (c ^ 16) : c;
        r1 = rg * 16 + rr;  c1 = cg * 32 + cs;
    }

    char* const A0h = smem + wr * 16384;
    char* const A1h = smem + 32768 + wr * 16384;
    char* const B0h = smem + 65536 + (wc >> 1) * 8192;
    char* const B1h = smem + 81920 + (wc >> 1) * 8192;
    const int bsub = (wc & 1) * 2;

    auto STG = [&](char* ldsb, const __hip_bfloat16* g) {
        gload_lds16(g + (size_t)r0 * H_ + c0, ldsb + wave * 1024);
        gload_lds16(g + (size_t)r1 * H_ + c1, ldsb + 8192 + wave * 1024);
    };
    auto STG1 = [&](char* ldsb, const __hip_bfloat16* g) {
        gload_lds16(g + (size_t)r0 * H_ + c0, ldsb + wave * 1024);
    };
    auto SRCA = [&](const __hip_bfloat16* P, int t, int hf) {
        return P + (size_t)(hf * 128) * H_ + (size_t)t * 64;
    };
    auto SRCB = [&](const __hip_bfloat16* P, int t, int hf) {
        return P + (size_t)(hf * 64) * H_ + (size_t)t * 64;
    };

    f32x4 acc[8][2] = {};

    STG (smem,          SRCA(Xp, 0, 0));
    STG (smem + 16384,  SRCA(Xp, 0, 1));
    STG1(smem + 65536,        SRCB(Wp, 0, 0));
    STG1(smem + 65536 + 8192, SRCB(Wp, 0, 1));
    STG1(smem + 81920,        SRCB(Wp, 1, 0));
    STG1(smem + 81920 + 8192, SRCB(Wp, 1, 1));
    WVM(2);
    BAR();

    const int NIT = H_ / 128;  // 16 iterations, 2 K-tiles each
    bf16x8 bfr[2][2];
    for (int j = 0; j < NIT; ++j) {
        const bool more = (j < NIT - 1);
        const int t1 = 2 * j + 1;
#pragma unroll
        for (int ph = 0; ph < 8; ++ph) {
            const int p = ph & 3;
            char* aA = (ph < 4) ? A0h : A1h;
            char* aB = (ph < 4) ? B0h : B1h;

            if (p == 0) {
#pragma unroll
                for (int jj = 0; jj < 2; ++jj)
#pragma unroll
                    for (int kk = 0; kk < 2; ++kk)
                        bfr[jj][kk] = *(const bf16x8*)(aB + ((bsub + jj) * 2 + kk) * 1024 + ro + co);
            }
            bf16x8 af[2][2];
#pragma unroll
            for (int i2 = 0; i2 < 2; ++i2)
#pragma unroll
                for (int kk = 0; kk < 2; ++kk)
                    af[i2][kk] = *(const bf16x8*)(aA + ((2 * p + i2) * 2 + kk) * 1024 + ro + co);

            if (ph == 0) { STG(smem + 32768, SRCA(Xp, t1, 0));
                           STG(smem + 49152, SRCA(Xp, t1, 1)); }
            else if (ph == 1 && more) STG1(smem + 65536,        SRCB(Wp, t1 + 1, 0));
            else if (ph == 2 && more) STG1(smem + 65536 + 8192, SRCB(Wp, t1 + 1, 1));
            else if (ph == 4 && more) STG (smem,                SRCA(Xp, t1 + 1, 0));
            else if (ph == 5 && more) STG (smem + 16384,        SRCA(Xp, t1 + 1, 1));
            else if (ph == 6 && more) STG1(smem + 81920,        SRCB(Wp, t1 + 2, 0));
            else if (ph == 7 && more) STG1(smem + 81920 + 8192, SRCB(Wp, t1 + 2, 1));

            if (ph == 3) { if (more) { WVM(2); } else { WVM(0); } }
            if (ph == 7 && more) { WVM(2); }

            BAR();
            WLG0();
            __builtin_amdgcn_sched_barrier(0);
            __builtin_amdgcn_s_setprio(1);
#pragma unroll
            for (int kk = 0; kk < 2; ++kk)
#pragma unroll
                for (int i2 = 0; i2 < 2; ++i2)
#pragma unroll
                    for (int jj = 0; jj < 2; ++jj)
                        acc[2 * p + i2][jj] = __builtin_amdgcn_mfma_f32_16x16x32_bf16(
                            af[i2][kk], bfr[jj][kk], acc[2 * p + i2][jj], 0, 0, 0);
            __builtin_amdgcn_s_setprio(0);
            BAR();
        }
    }

    if (EPI == 2) {
        __hip_bfloat16* VTo = (__hip_bfloat16*)Cout;
#pragma unroll
        for (int i = 0; i < 8; ++i) {
            int tok = bm * 256 + wr * 128 + i * 16 + quad * 4;
            int b = tok >> 11, s = tok & (S_ - 1);
#pragma unroll
            for (int jj = 0; jj < 2; ++jj) {
                int col = bn * 128 + (wc >> 1) * 64 + (wc & 1) * 32 + jj * 16 + l16;
                int h = col >> 7, d = col & 127;
                float bv = bias[col];
                bf16x4 v;
#pragma unroll
                for (int r = 0; r < 4; ++r)
                    v[r] = (short)f2bfu(acc[i][jj][r] + bv);
                *(bf16x4*)(VTo + ((size_t)(b * 16 + h) * 128 + d) * S_ + s) = v;
            }
        }
    } else {
#pragma unroll
        for (int i = 0; i < 8; ++i) {
            int row = bm * 256 + wr * 128 + i * 16 + quad * 4;
#pragma unroll
            for (int jj = 0; jj < 2; ++jj) {
                int col = bn * 128 + (wc >> 1) * 64 + (wc & 1) * 32 + jj * 16 + l16;
                float bv = bias[col];
#pragma unroll
                for (int r = 0; r < 4; ++r)
                    ((__hip_bfloat16*)Cout)[(size_t)(row + r) * H_ + col] =
                        __float2bfloat16(acc[i][jj][r] + bv);
            }
        }
    }
}

// fused QKV: 768 blocks = 3 exact rounds; bn-FASTEST swizzle (verified: FETCH 123 MB)
__global__ __launch_bounds__(512, 2)
void gemm_qkv8(const __hip_bfloat16* __restrict__ X,
               const __hip_bfloat16* __restrict__ Wq, const __hip_bfloat16* __restrict__ Wk,
               const __hip_bfloat16* __restrict__ Wv,
               const float* __restrict__ bq, const float* __restrict__ bk,
               const float* __restrict__ bv,
               __hip_bfloat16* __restrict__ Qo, __hip_bfloat16* __restrict__ Ko,
               __hip_bfloat16* __restrict__ VTo)
{
    __shared__ __align__(16) char smem[98304];

    const int bid = blockIdx.x;
    const int swz = (bid & 7) * 96 + (bid >> 3);   // bijective (768 % 8 == 0)
    const int sel = swz >> 8;            // 0=Q 1=K 2=V (256 tiles each)
    const int rem = swz & 255;
    const int bn  = rem & 15;            // N tile fastest
    const int bm  = rem >> 4;            // M tile

    const __hip_bfloat16* W = (sel == 0) ? Wq : (sel == 1) ? Wk : Wv;
    const float* bias       = (sel == 0) ? bq : (sel == 1) ? bk : bv;

    const __hip_bfloat16* Xp = X + (size_t)(bm * 256) * H_;
    const __hip_bfloat16* Wp = W + (size_t)(bn * 128) * H_;

    if (sel == 2)
        gemm256x128_body<2>(Xp, Wp, bias, VTo, bm, bn, smem);
    else
        gemm256x128_body<1>(Xp, Wp, bias, (sel == 0) ? Qo : Ko, bm, bn, smem);
}

// ---------------------------------------------------------------- flash attention v9: q-pair blocks
// Each block owns TWO q-tiles (2u, 2u+1) of one head, sharing K/V tiles: 512 blocks.
// - Round-9 audit: old 1024-block map gave every CU 4 blocks of the SAME causal depth
//   (q&31 invariant under +256-lid strides) -> ~52% machine efficiency. New map pairs
//   depth u with 15-u across dispatch rounds -> per-CU work uniform (34 iter-units).
// - kf/vf LDS reads shared by both tiles' MFMAs (halves LDS traffic); QK/PV of one tile
//   overlaps softmax VALU of the other (intra-wave ILP).
// - K/V double-buffered, prefetch at iter top, one barrier per iter (round-9 hazard scheme).
__global__ __launch_bounds__(256, 2)
void attn_kernel(const __hip_bfloat16* __restrict__ Q,
                 const __hip_bfloat16* __restrict__ K,
                 const __hip_bfloat16* __restrict__ VT,   // [(b*16+h)*128 + d][s]
                 __hip_bfloat16* __restrict__ O)
{
    __shared__ __align__(16) char Ks[2][16384];   // K-tile: 64 key-rows x 256B
    __shared__ __align__(16) char Vt[2][16384];   // V^T-tile: 128 d-rows x 128B

    const int tid  = threadIdx.x;
    const int wave = tid >> 6, lane = tid & 63;
    const int quad = lane >> 4, l16 = lane & 15;

    const int lid = blockIdx.x;                  // 0..511
    const int xcd = lid & 7;
    const int q   = lid >> 3;                    // 0..63
    const int grp = q >> 4;                      // 0..3
    const int k15 = q & 15;
    const int bh  = (grp << 3) | xcd;            // 0..31
    const int u   = (grp < 2) ? (15 - k15) : k15;   // complementary across rounds
    const int b   = bh >> 4, h = bh & 15;
    const int qbA = 2 * u, qbB = 2 * u + 1;

    const size_t headoff = (size_t)b * S_ * H_ + (size_t)h * HD_;
    const __hip_bfloat16* Qp  = Q + headoff;
    const __hip_bfloat16* Kp  = K + headoff;
    const __hip_bfloat16* Vtp = VT + (size_t)(b * 16 + h) * 128 * S_;

    const float scale  = 0.08838834764831843f;    // 1/sqrt(128)
    const float THRraw = 90.50966799187809f;      // 8 / scale
    const int A0 = (((quad & 1) * 2) * 16 + l16) * 4;
    const int A1 = A0 + 64;
    const bool hiq = (quad >= 2);

    const int qrow_local = wave * 16;
    const int qrowA = qbA * 64 + qrow_local;
    const int qrowB = qbB * 64 + qrow_local;

    bf16x8 qfA[4], qfB[4];
#pragma unroll
    for (int kd = 0; kd < 4; ++kd) {
        qfA[kd] = *(const bf16x8*)(Qp + (size_t)(qrowA + l16) * H_ + kd * 32 + quad * 8);
        qfB[kd] = *(const bf16x8*)(Qp + (size_t)(qrowB + l16) * H_ + kd * 32 + quad * 8);
    }

    f32x4 oaccA[8] = {}, oaccB[8] = {};
    float miA = -1e30f, liA = 0.0f;
    float miB = -1e30f, liB = 0.0f;

    // softmax + C->A transform for one tile; updates (mi, li, oacc-rescale), emits pf
    auto sm_xform = [&](f32x4 (&sacc)[4], float& mi, float& li, f32x4 (&oacc)[8],
                        bool diag, bf16x8 (&pf)[2]) {
        float p[4][4];
        float tm = -1e30f;
#pragma unroll
        for (int cb = 0; cb < 4; ++cb)
#pragma unroll
            for (int r = 0; r < 4; ++r) {
                float s = sacc[cb][r];           // RAW; scale folded into exp
                if (diag) {
                    int keyl = cb * 16 + quad * 4 + r;
                    if (keyl > qrow_local + l16) s = -1e30f;
                }
                p[cb][r] = s;
                tm = fmaxf(tm, s);
            }
        tm = fmaxf(tm, __shfl_xor(tm, 16));
        tm = fmaxf(tm, __shfl_xor(tm, 32));

        const bool noresc = __all(tm - mi <= THRraw);
        float mnew = noresc ? mi : fmaxf(mi, tm);
        float ms = mnew * scale;

        float sum = 0.0f;
#pragma unroll
        for (int cb = 0; cb < 4; ++cb)
#pragma unroll
            for (int r = 0; r < 4; ++r) {
                float e = __expf(__builtin_fmaf(p[cb][r], scale, -ms));
                p[cb][r] = e;
                sum += e;
            }
        sum += __shfl_xor(sum, 16);
        sum += __shfl_xor(sum, 32);

        if (noresc) {
            li = li + sum;
        } else {
            float alpha = __expf((mi - mnew) * scale);
            li = li * alpha + sum;
            float ar[4];
#pragma unroll
            for (int r = 0; r < 4; ++r)
                ar[r] = __shfl(alpha, quad * 4 + r);
#pragma unroll
            for (int db = 0; db < 8; ++db)
#pragma unroll
                for (int r = 0; r < 4; ++r)
                    oacc[db][r] *= ar[r];
        }
        mi = mnew;

        int Pp[4][2];
#pragma unroll
        for (int cb = 0; cb < 4; ++cb) {
            Pp[cb][0] = packbf(p[cb][0], p[cb][1]);
            Pp[cb][1] = packbf(p[cb][2], p[cb][3]);
        }
#pragma unroll
        for (int ks = 0; ks < 2; ++ks) {
            int c0 = 2 * ks, c1 = 2 * ks + 1;
            int d0 = __builtin_amdgcn_ds_bpermute(A0, Pp[c0][0]);
            int e0 = __builtin_amdgcn_ds_bpermute(A0, Pp[c1][0]);
            int d1 = __builtin_amdgcn_ds_bpermute(A0, Pp[c0][1]);
            int e1 = __builtin_amdgcn_ds_bpermute(A0, Pp[c1][1]);
            int d2 = __builtin_amdgcn_ds_bpermute(A1, Pp[c0][0]);
            int e2 = __builtin_amdgcn_ds_bpermute(A1, Pp[c1][0]);
            int d3 = __builtin_amdgcn_ds_bpermute(A1, Pp[c0][1]);
            int e3 = __builtin_amdgcn_ds_bpermute(A1, Pp[c1][1]);
            union { int i[4]; bf16x8 v; } w;
            w.i[0] = hiq ? e0 : d0;
            w.i[1] = hiq ? e1 : d1;
            w.i[2] = hiq ? e2 : d2;
            w.i[3] = hiq ? e3 : d3;
            pf[ks] = w.v;
        }
    };

    // prologue: tile 0 -> buf 0
#pragma unroll
    for (int t = 0; t < 4; ++t) {
        int c = wave * 256 + t * 64 + lane;
        int krow = c >> 4, kpos = c & 15;
        gload_lds16(Kp + (size_t)krow * H_ + (kpos ^ (krow & 7)) * 8,
                    &Ks[0][(wave * 256 + t * 64) * 16]);
        int vrow = c >> 3, vpos = c & 7;
        gload_lds16(Vtp + (size_t)vrow * S_ + (vpos ^ (vrow & 7)) * 8,
                    &Vt[0][(wave * 256 + t * 64) * 16]);
    }
    __syncthreads();

    for (int kb = 0; kb <= qbB; ++kb) {
        const int cur = kb & 1;
        const bool more   = (kb < qbB);
        const bool aliveA = (kb <= qbA);         // block-uniform

        if (more) {
            const __hip_bfloat16* Kn = Kp + (size_t)(kb + 1) * 64 * H_;
            const int vcol = (kb + 1) * 64;
#pragma unroll
            for (int t = 0; t < 4; ++t) {
                int c = wave * 256 + t * 64 + lane;
                int krow = c >> 4, kpos = c & 15;
                gload_lds16(Kn + (size_t)krow * H_ + (kpos ^ (krow & 7)) * 8,
                            &Ks[cur ^ 1][(wave * 256 + t * 64) * 16]);
                int vrow = c >> 3, vpos = c & 7;
                gload_lds16(Vtp + (size_t)vrow * S_ + vcol + (vpos ^ (vrow & 7)) * 8,
                            &Vt[cur ^ 1][(wave * 256 + t * 64) * 16]);
            }
        }

        // ---- QK for both tiles, kf shared (A's result unused on final iteration)
        f32x4 saccA[4] = {}, saccB[4] = {};
#pragma unroll
        for (int cb = 0; cb < 4; ++cb) {
#pragma unroll
            for (int kd = 0; kd < 4; ++kd) {
                int row = cb * 16 + l16;
                int pos = (4 * kd + quad) ^ (l16 & 7);
                bf16x8 kf = *(const bf16x8*)&Ks[cur][row * 256 + pos * 16];
                saccA[cb] = __builtin_amdgcn_mfma_f32_16x16x32_bf16(kf, qfA[kd], saccA[cb], 0, 0, 0);
                saccB[cb] = __builtin_amdgcn_mfma_f32_16x16x32_bf16(kf, qfB[kd], saccB[cb], 0, 0, 0);
            }
        }

        bf16x8 pfA[2], pfB[2];
        if (aliveA) sm_xform(saccA, miA, liA, oaccA, kb == qbA, pfA);
        sm_xform(saccB, miB, liB, oaccB, kb == qbB, pfB);

        // ---- PV for both tiles, vf shared
        if (aliveA) {
#pragma unroll
            for (int ks = 0; ks < 2; ++ks)
#pragma unroll
                for (int db = 0; db < 8; ++db) {
                    int vrow = db * 16 + l16;
                    int vpos = (ks * 4 + quad) ^ (l16 & 7);
                    bf16x8 vf = *(const bf16x8*)&Vt[cur][vrow * 128 + vpos * 16];
                    oaccA[db] = __builtin_amdgcn_mfma_f32_16x16x32_bf16(pfA[ks], vf, oaccA[db], 0, 0, 0);
                    oaccB[db] = __builtin_amdgcn_mfma_f32_16x16x32_bf16(pfB[ks], vf, oaccB[db], 0, 0, 0);
                }
        } else {
#pragma unroll
            for (int ks = 0; ks < 2; ++ks)
#pragma unroll
                for (int db = 0; db < 8; ++db) {
                    int vrow = db * 16 + l16;
                    int vpos = (ks * 4 + quad) ^ (l16 & 7);
                    bf16x8 vf = *(const bf16x8*)&Vt[cur][vrow * 128 + vpos * 16];
                    oaccB[db] = __builtin_amdgcn_mfma_f32_16x16x32_bf16(pfB[ks], vf, oaccB[db], 0, 0, 0);
                }
        }

        __syncthreads();   // all reads of buf cur done + prefetch DMA landed
    }

    // ---- epilogue: both tiles
    {
        float lr[4];
#pragma unroll
        for (int r = 0; r < 4; ++r)
            lr[r] = __shfl(liA, quad * 4 + r);
#pragma unroll
        for (int db = 0; db < 8; ++db)
#pragma unroll
            for (int r = 0; r < 4; ++r) {
                float v = oaccA[db][r] / lr[r];
                size_t row = (size_t)b * S_ + qrowA + quad * 4 + r;
                O[row * H_ + h * HD_ + db * 16 + l16] = __float2bfloat16(v);
            }
    }
    {
        float lr[4];
#pragma unroll
        for (int r = 0; r < 4; ++r)
            lr[r] = __shfl(liB, quad * 4 + r);
#pragma unroll
        for (int db = 0; db < 8; ++db)
#pragma unroll
            for (int r = 0; r < 4; ++r) {
                float v = oaccB[db][r] / lr[r];
                size_t row = (size_t)b * S_ + qrowB + quad * 4 + r;
                O[row * H_ + h * HD_ + db * 16 + l16] = __float2bfloat16(v);
            }
    }
}

// ---------------------------------------------------------------- launcher
extern "C" void kernel_launch(void* const* d_in, const int* in_sizes, int n_in,
                              void* d_out, int out_size, void* d_ws, size_t ws_size,
                              hipStream_t stream)
{
    const float* hs = (const float*)d_in[0];
    const float* Wq = (const float*)d_in[2];
    const float* bq = (const float*)d_in[3];
    const float* Wk = (const float*)d_in[4];
    const float* bk = (const float*)d_in[5];
    const float* Wv = (const float*)d_in[6];
    const float* bv = (const float*)d_in[7];
    const float* Wo = (const float*)d_in[8];
    const float* bo = (const float*)d_in[9];

    const size_t szX = (size_t)MTOT * H_;
    const size_t szW = (size_t)H_ * H_;

    __hip_bfloat16* Xbf = (__hip_bfloat16*)d_ws;   // reused as attention output
    __hip_bfloat16* Wqb = Xbf + szX;
    __hip_bfloat16* Wkb = Wqb + szW;
    __hip_bfloat16* Wvb = Wkb + szW;
    __hip_bfloat16* Wob = Wvb + szW;
    __hip_bfloat16* Qb  = Wob + szW;
    __hip_bfloat16* Kb  = Qb + szX;
    __hip_bfloat16* VTb = Kb + szX;                // V^T [(b*16+h)*128+d][s]

    castall<<<dim3(4096, 6), 256, 0, stream>>>(hs, Wq, Wk, Wv, Wo, Xbf, Wqb, Wkb, Wvb, Wob);

    gemm_qkv8<<<dim3(768), 512, 0, stream>>>(Xbf, Wqb, Wkb, Wvb, bq, bk, bv, Qb, Kb, VTb);

    attn_kernel<<<dim3(512), 256, 0, stream>>>(Qb, Kb, VTb, Xbf);

    gemm_out<<<dim3(16, 32), 256, 0, stream>>>(Xbf, Wob, bo, (float*)d_out);
}

// Round 11
// 371.637 us; speedup vs baseline: 1.1092x; 1.0512x over previous
//
#include <hip/hip_runtime.h>
#include <hip/hip_bf16.h>
#include <stdint.h>

#define B_   2
#define S_   2048
#define H_   2048
#define NH_  16
#define HD_  128
#define MTOT (B_*S_)   // 4096

typedef __attribute__((ext_vector_type(8))) short bf16x8;   // 8 bf16 = 4 VGPRs
typedef __attribute__((ext_vector_type(4))) short bf16x4;   // 8B packed store
typedef __attribute__((ext_vector_type(4))) float f32x4;    // MFMA C/D

__device__ __forceinline__ void gload_lds16(const void* g, void* l) {
    __builtin_amdgcn_global_load_lds(
        (const __attribute__((address_space(1))) void*)g,
        (__attribute__((address_space(3))) void*)l, 16, 0, 0);
}

__device__ __forceinline__ unsigned short f2bfu(float x) {
    __hip_bfloat16 h = __float2bfloat16(x);
    return *reinterpret_cast<unsigned short*>(&h);
}
__device__ __forceinline__ int packbf(float a, float b) {
    return (int)f2bfu(a) | ((int)f2bfu(b) << 16);
}

#define BAR()  asm volatile("s_barrier" ::: "memory")
#define WLG0() asm volatile("s_waitcnt lgkmcnt(0)" ::: "memory")
#define WVM(n) asm volatile("s_waitcnt vmcnt(" #n ")" ::: "memory")

// ---------------------------------------------------------------- fused fp32 -> bf16 casts
__global__ void castall(const float* __restrict__ hs,
                        const float* __restrict__ w0, const float* __restrict__ w1,
                        const float* __restrict__ w2, const float* __restrict__ w3,
                        __hip_bfloat16* __restrict__ xb,
                        __hip_bfloat16* __restrict__ o0, __hip_bfloat16* __restrict__ o1,
                        __hip_bfloat16* __restrict__ o2, __hip_bfloat16* __restrict__ o3)
{
    const size_t Q = 1048576;   // float4s per region
    const float* in; __hip_bfloat16* out; size_t base = 0;
    switch (blockIdx.y) {
        case 0:  in = hs; out = xb; break;
        case 1:  in = hs; out = xb; base = Q; break;
        case 2:  in = w0; out = o0; break;
        case 3:  in = w1; out = o1; break;
        case 4:  in = w2; out = o2; break;
        default: in = w3; out = o3; break;
    }
    size_t i = base + (size_t)blockIdx.x * 256 + threadIdx.x;
    float4 v = *(const float4*)(in + i * 4);
    uint2 o;
    o.x = (unsigned)packbf(v.x, v.y);
    o.y = (unsigned)packbf(v.z, v.w);
    *(uint2*)((char*)out + i * 8) = o;
}

// ---------------------------------------------------------------- 256x128 8-phase GEMM body
// Verified rounds 7-10 in qkv8: 768 tiles in 119.4 us = 39.8 us per 256-tile round,
// bank-conflict 0, FETCH 123 MB with bn-fastest swizzle.
template<int EPI>   // 0 = fp32+bias, 1 = bf16+bias, 2 = bf16 V^T scatter
__device__ __forceinline__ void gemm256x128_body(const __hip_bfloat16* __restrict__ Xp,
                                                 const __hip_bfloat16* __restrict__ Wp,
                                                 const float* __restrict__ bias,
                                                 void* __restrict__ Cout,
                                                 int bm, int bn, char* smem)
{
    const int tid  = threadIdx.x;
    const int wave = tid >> 6, lane = tid & 63;
    const int quad = lane >> 4, l16 = lane & 15;
    const int wr = wave >> 2, wc = wave & 3;       // 2 x 4 wave grid; per-wave out 128x32

    const int ro = l16 * 64;
    const int co = (((l16 & 8) ? ((quad * 8) ^ 16) : (quad * 8)) << 1);

    int r0, c0, r1, c1;
    {
        int D = tid * 16;
        int rg = D >> 11, cg = (D >> 10) & 1;
        int rr = (D >> 6) & 15, c = (D & 63) >> 1;
        int cs = (rr & 8) ? (c ^ 16) : c;
        r0 = rg * 16 + rr;  c0 = cg * 32 + cs;
        D = 8192 + tid * 16;
        rg = D >> 11; cg = (D >> 10) & 1;
        rr = (D >> 6) & 15; c = (D & 63) >> 1;
        cs = (rr & 8) ? (c ^ 16) : c;
        r1 = rg * 16 + rr;  c1 = cg * 32 + cs;
    }

    char* const A0h = smem + wr * 16384;
    char* const A1h = smem + 32768 + wr * 16384;
    char* const B0h = smem + 65536 + (wc >> 1) * 8192;
    char* const B1h = smem + 81920 + (wc >> 1) * 8192;
    const int bsub = (wc & 1) * 2;

    auto STG = [&](char* ldsb, const __hip_bfloat16* g) {
        gload_lds16(g + (size_t)r0 * H_ + c0, ldsb + wave * 1024);
        gload_lds16(g + (size_t)r1 * H_ + c1, ldsb + 8192 + wave * 1024);
    };
    auto STG1 = [&](char* ldsb, const __hip_bfloat16* g) {
        gload_lds16(g + (size_t)r0 * H_ + c0, ldsb + wave * 1024);
    };
    auto SRCA = [&](const __hip_bfloat16* P, int t, int hf) {
        return P + (size_t)(hf * 128) * H_ + (size_t)t * 64;
    };
    auto SRCB = [&](const __hip_bfloat16* P, int t, int hf) {
        return P + (size_t)(hf * 64) * H_ + (size_t)t * 64;
    };

    f32x4 acc[8][2] = {};

    STG (smem,          SRCA(Xp, 0, 0));
    STG (smem + 16384,  SRCA(Xp, 0, 1));
    STG1(smem + 65536,        SRCB(Wp, 0, 0));
    STG1(smem + 65536 + 8192, SRCB(Wp, 0, 1));
    STG1(smem + 81920,        SRCB(Wp, 1, 0));
    STG1(smem + 81920 + 8192, SRCB(Wp, 1, 1));
    WVM(2);
    BAR();

    const int NIT = H_ / 128;  // 16 iterations, 2 K-tiles each
    bf16x8 bfr[2][2];
    for (int j = 0; j < NIT; ++j) {
        const bool more = (j < NIT - 1);
        const int t1 = 2 * j + 1;
#pragma unroll
        for (int ph = 0; ph < 8; ++ph) {
            const int p = ph & 3;
            char* aA = (ph < 4) ? A0h : A1h;
            char* aB = (ph < 4) ? B0h : B1h;

            if (p == 0) {
#pragma unroll
                for (int jj = 0; jj < 2; ++jj)
#pragma unroll
                    for (int kk = 0; kk < 2; ++kk)
                        bfr[jj][kk] = *(const bf16x8*)(aB + ((bsub + jj) * 2 + kk) * 1024 + ro + co);
            }
            bf16x8 af[2][2];
#pragma unroll
            for (int i2 = 0; i2 < 2; ++i2)
#pragma unroll
                for (int kk = 0; kk < 2; ++kk)
                    af[i2][kk] = *(const bf16x8*)(aA + ((2 * p + i2) * 2 + kk) * 1024 + ro + co);

            if (ph == 0) { STG(smem + 32768, SRCA(Xp, t1, 0));
                           STG(smem + 49152, SRCA(Xp, t1, 1)); }
            else if (ph == 1 && more) STG1(smem + 65536,        SRCB(Wp, t1 + 1, 0));
            else if (ph == 2 && more) STG1(smem + 65536 + 8192, SRCB(Wp, t1 + 1, 1));
            else if (ph == 4 && more) STG (smem,                SRCA(Xp, t1 + 1, 0));
            else if (ph == 5 && more) STG (smem + 16384,        SRCA(Xp, t1 + 1, 1));
            else if (ph == 6 && more) STG1(smem + 81920,        SRCB(Wp, t1 + 2, 0));
            else if (ph == 7 && more) STG1(smem + 81920 + 8192, SRCB(Wp, t1 + 2, 1));

            if (ph == 3) { if (more) { WVM(2); } else { WVM(0); } }
            if (ph == 7 && more) { WVM(2); }

            BAR();
            WLG0();
            __builtin_amdgcn_sched_barrier(0);
            __builtin_amdgcn_s_setprio(1);
#pragma unroll
            for (int kk = 0; kk < 2; ++kk)
#pragma unroll
                for (int i2 = 0; i2 < 2; ++i2)
#pragma unroll
                    for (int jj = 0; jj < 2; ++jj)
                        acc[2 * p + i2][jj] = __builtin_amdgcn_mfma_f32_16x16x32_bf16(
                            af[i2][kk], bfr[jj][kk], acc[2 * p + i2][jj], 0, 0, 0);
            __builtin_amdgcn_s_setprio(0);
            BAR();
        }
    }

    if (EPI == 2) {
        __hip_bfloat16* VTo = (__hip_bfloat16*)Cout;
#pragma unroll
        for (int i = 0; i < 8; ++i) {
            int tok = bm * 256 + wr * 128 + i * 16 + quad * 4;
            int b = tok >> 11, s = tok & (S_ - 1);
#pragma unroll
            for (int jj = 0; jj < 2; ++jj) {
                int col = bn * 128 + (wc >> 1) * 64 + (wc & 1) * 32 + jj * 16 + l16;
                int h = col >> 7, d = col & 127;
                float bv = bias[col];
                bf16x4 v;
#pragma unroll
                for (int r = 0; r < 4; ++r)
                    v[r] = (short)f2bfu(acc[i][jj][r] + bv);
                *(bf16x4*)(VTo + ((size_t)(b * 16 + h) * 128 + d) * S_ + s) = v;
            }
        }
    } else {
#pragma unroll
        for (int i = 0; i < 8; ++i) {
            int row = bm * 256 + wr * 128 + i * 16 + quad * 4;
#pragma unroll
            for (int jj = 0; jj < 2; ++jj) {
                int col = bn * 128 + (wc >> 1) * 64 + (wc & 1) * 32 + jj * 16 + l16;
                float bv = bias[col];
#pragma unroll
                for (int r = 0; r < 4; ++r) {
                    float v = acc[i][jj][r] + bv;
                    if (EPI == 1)
                        ((__hip_bfloat16*)Cout)[(size_t)(row + r) * H_ + col] = __float2bfloat16(v);
                    else
                        ((float*)Cout)[(size_t)(row + r) * H_ + col] = v;
                }
            }
        }
    }
}

// fused QKV: 768 blocks = 3 exact rounds; bn-FASTEST swizzle (verified: FETCH 123 MB)
__global__ __launch_bounds__(512, 2)
void gemm_qkv8(const __hip_bfloat16* __restrict__ X,
               const __hip_bfloat16* __restrict__ Wq, const __hip_bfloat16* __restrict__ Wk,
               const __hip_bfloat16* __restrict__ Wv,
               const float* __restrict__ bq, const float* __restrict__ bk,
               const float* __restrict__ bv,
               __hip_bfloat16* __restrict__ Qo, __hip_bfloat16* __restrict__ Ko,
               __hip_bfloat16* __restrict__ VTo)
{
    __shared__ __align__(16) char smem[98304];

    const int bid = blockIdx.x;
    const int swz = (bid & 7) * 96 + (bid >> 3);   // bijective (768 % 8 == 0)
    const int sel = swz >> 8;            // 0=Q 1=K 2=V (256 tiles each)
    const int rem = swz & 255;
    const int bn  = rem & 15;            // N tile fastest
    const int bm  = rem >> 4;            // M tile

    const __hip_bfloat16* W = (sel == 0) ? Wq : (sel == 1) ? Wk : Wv;
    const float* bias       = (sel == 0) ? bq : (sel == 1) ? bk : bv;

    const __hip_bfloat16* Xp = X + (size_t)(bm * 256) * H_;
    const __hip_bfloat16* Wp = W + (size_t)(bn * 128) * H_;

    if (sel == 2)
        gemm256x128_body<2>(Xp, Wp, bias, VTo, bm, bn, smem);
    else
        gemm256x128_body<1>(Xp, Wp, bias, (sel == 0) ? Qo : Ko, bm, bn, smem);
}

// O-projection on the SAME verified body: 16x16 = 256 tiles = exactly ONE full round.
// qkv8 measured 39.8 us/round at this tile shape and K; fp32 epilogue adds ~3-5 us.
__global__ __launch_bounds__(512, 2)
void gemm_out8(const __hip_bfloat16* __restrict__ A, const __hip_bfloat16* __restrict__ W,
               const float* __restrict__ bias, float* __restrict__ C)
{
    __shared__ __align__(16) char smem[98304];
    const int bid = blockIdx.x;                  // 0..255
    const int swz = (bid & 7) * 32 + (bid >> 3); // bijective (256 % 8 == 0)
    const int bn  = swz & 15;                    // N tile fastest (2 A-panels/XCD resident)
    const int bm  = swz >> 4;                    // M tile
    gemm256x128_body<0>(A + (size_t)(bm * 256) * H_, W + (size_t)(bn * 128) * H_,
                        bias, C, bm, bn, smem);
}

// ---------------------------------------------------------------- flash attention v9: q-pair blocks
// (verified round 10: 512 blocks, depth-paired load balance, K/V-shared 2-tile MFMAs, ~-20 us)
__global__ __launch_bounds__(256, 2)
void attn_kernel(const __hip_bfloat16* __restrict__ Q,
                 const __hip_bfloat16* __restrict__ K,
                 const __hip_bfloat16* __restrict__ VT,   // [(b*16+h)*128 + d][s]
                 __hip_bfloat16* __restrict__ O)
{
    __shared__ __align__(16) char Ks[2][16384];   // K-tile: 64 key-rows x 256B
    __shared__ __align__(16) char Vt[2][16384];   // V^T-tile: 128 d-rows x 128B

    const int tid  = threadIdx.x;
    const int wave = tid >> 6, lane = tid & 63;
    const int quad = lane >> 4, l16 = lane & 15;

    const int lid = blockIdx.x;                  // 0..511
    const int xcd = lid & 7;
    const int q   = lid >> 3;                    // 0..63
    const int grp = q >> 4;                      // 0..3
    const int k15 = q & 15;
    const int bh  = (grp << 3) | xcd;            // 0..31
    const int u   = (grp < 2) ? (15 - k15) : k15;   // complementary across rounds
    const int b   = bh >> 4, h = bh & 15;
    const int qbA = 2 * u, qbB = 2 * u + 1;

    const size_t headoff = (size_t)b * S_ * H_ + (size_t)h * HD_;
    const __hip_bfloat16* Qp  = Q + headoff;
    const __hip_bfloat16* Kp  = K + headoff;
    const __hip_bfloat16* Vtp = VT + (size_t)(b * 16 + h) * 128 * S_;

    const float scale  = 0.08838834764831843f;    // 1/sqrt(128)
    const float THRraw = 90.50966799187809f;      // 8 / scale
    const int A0 = (((quad & 1) * 2) * 16 + l16) * 4;
    const int A1 = A0 + 64;
    const bool hiq = (quad >= 2);

    const int qrow_local = wave * 16;
    const int qrowA = qbA * 64 + qrow_local;
    const int qrowB = qbB * 64 + qrow_local;

    bf16x8 qfA[4], qfB[4];
#pragma unroll
    for (int kd = 0; kd < 4; ++kd) {
        qfA[kd] = *(const bf16x8*)(Qp + (size_t)(qrowA + l16) * H_ + kd * 32 + quad * 8);
        qfB[kd] = *(const bf16x8*)(Qp + (size_t)(qrowB + l16) * H_ + kd * 32 + quad * 8);
    }

    f32x4 oaccA[8] = {}, oaccB[8] = {};
    float miA = -1e30f, liA = 0.0f;
    float miB = -1e30f, liB = 0.0f;

    auto sm_xform = [&](f32x4 (&sacc)[4], float& mi, float& li, f32x4 (&oacc)[8],
                        bool diag, bf16x8 (&pf)[2]) {
        float p[4][4];
        float tm = -1e30f;
#pragma unroll
        for (int cb = 0; cb < 4; ++cb)
#pragma unroll
            for (int r = 0; r < 4; ++r) {
                float s = sacc[cb][r];           // RAW; scale folded into exp
                if (diag) {
                    int keyl = cb * 16 + quad * 4 + r;
                    if (keyl > qrow_local + l16) s = -1e30f;
                }
                p[cb][r] = s;
                tm = fmaxf(tm, s);
            }
        tm = fmaxf(tm, __shfl_xor(tm, 16));
        tm = fmaxf(tm, __shfl_xor(tm, 32));

        const bool noresc = __all(tm - mi <= THRraw);
        float mnew = noresc ? mi : fmaxf(mi, tm);
        float ms = mnew * scale;

        float sum = 0.0f;
#pragma unroll
        for (int cb = 0; cb < 4; ++cb)
#pragma unroll
            for (int r = 0; r < 4; ++r) {
                float e = __expf(__builtin_fmaf(p[cb][r], scale, -ms));
                p[cb][r] = e;
                sum += e;
            }
        sum += __shfl_xor(sum, 16);
        sum += __shfl_xor(sum, 32);

        if (noresc) {
            li = li + sum;
        } else {
            float alpha = __expf((mi - mnew) * scale);
            li = li * alpha + sum;
            float ar[4];
#pragma unroll
            for (int r = 0; r < 4; ++r)
                ar[r] = __shfl(alpha, quad * 4 + r);
#pragma unroll
            for (int db = 0; db < 8; ++db)
#pragma unroll
                for (int r = 0; r < 4; ++r)
                    oacc[db][r] *= ar[r];
        }
        mi = mnew;

        int Pp[4][2];
#pragma unroll
        for (int cb = 0; cb < 4; ++cb) {
            Pp[cb][0] = packbf(p[cb][0], p[cb][1]);
            Pp[cb][1] = packbf(p[cb][2], p[cb][3]);
        }
#pragma unroll
        for (int ks = 0; ks < 2; ++ks) {
            int c0 = 2 * ks, c1 = 2 * ks + 1;
            int d0 = __builtin_amdgcn_ds_bpermute(A0, Pp[c0][0]);
            int e0 = __builtin_amdgcn_ds_bpermute(A0, Pp[c1][0]);
            int d1 = __builtin_amdgcn_ds_bpermute(A0, Pp[c0][1]);
            int e1 = __builtin_amdgcn_ds_bpermute(A0, Pp[c1][1]);
            int d2 = __builtin_amdgcn_ds_bpermute(A1, Pp[c0][0]);
            int e2 = __builtin_amdgcn_ds_bpermute(A1, Pp[c1][0]);
            int d3 = __builtin_amdgcn_ds_bpermute(A1, Pp[c0][1]);
            int e3 = __builtin_amdgcn_ds_bpermute(A1, Pp[c1][1]);
            union { int i[4]; bf16x8 v; } w;
            w.i[0] = hiq ? e0 : d0;
            w.i[1] = hiq ? e1 : d1;
            w.i[2] = hiq ? e2 : d2;
            w.i[3] = hiq ? e3 : d3;
            pf[ks] = w.v;
        }
    };

    // prologue: tile 0 -> buf 0
#pragma unroll
    for (int t = 0; t < 4; ++t) {
        int c = wave * 256 + t * 64 + lane;
        int krow = c >> 4, kpos = c & 15;
        gload_lds16(Kp + (size_t)krow * H_ + (kpos ^ (krow & 7)) * 8,
                    &Ks[0][(wave * 256 + t * 64) * 16]);
        int vrow = c >> 3, vpos = c & 7;
        gload_lds16(Vtp + (size_t)vrow * S_ + (vpos ^ (vrow & 7)) * 8,
                    &Vt[0][(wave * 256 + t * 64) * 16]);
    }
    __syncthreads();

    for (int kb = 0; kb <= qbB; ++kb) {
        const int cur = kb & 1;
        const bool more   = (kb < qbB);
        const bool aliveA = (kb <= qbA);         // block-uniform

        if (more) {
            const __hip_bfloat16* Kn = Kp + (size_t)(kb + 1) * 64 * H_;
            const int vcol = (kb + 1) * 64;
#pragma unroll
            for (int t = 0; t < 4; ++t) {
                int c = wave * 256 + t * 64 + lane;
                int krow = c >> 4, kpos = c & 15;
                gload_lds16(Kn + (size_t)krow * H_ + (kpos ^ (krow & 7)) * 8,
                            &Ks[cur ^ 1][(wave * 256 + t * 64) * 16]);
                int vrow = c >> 3, vpos = c & 7;
                gload_lds16(Vtp + (size_t)vrow * S_ + vcol + (vpos ^ (vrow & 7)) * 8,
                            &Vt[cur ^ 1][(wave * 256 + t * 64) * 16]);
            }
        }

        f32x4 saccA[4] = {}, saccB[4] = {};
#pragma unroll
        for (int cb = 0; cb < 4; ++cb) {
#pragma unroll
            for (int kd = 0; kd < 4; ++kd) {
                int row = cb * 16 + l16;
                int pos = (4 * kd + quad) ^ (l16 & 7);
                bf16x8 kf = *(const bf16x8*)&Ks[cur][row * 256 + pos * 16];
                saccA[cb] = __builtin_amdgcn_mfma_f32_16x16x32_bf16(kf, qfA[kd], saccA[cb], 0, 0, 0);
                saccB[cb] = __builtin_amdgcn_mfma_f32_16x16x32_bf16(kf, qfB[kd], saccB[cb], 0, 0, 0);
            }
        }

        bf16x8 pfA[2], pfB[2];
        if (aliveA) sm_xform(saccA, miA, liA, oaccA, kb == qbA, pfA);
        sm_xform(saccB, miB, liB, oaccB, kb == qbB, pfB);

        if (aliveA) {
#pragma unroll
            for (int ks = 0; ks < 2; ++ks)
#pragma unroll
                for (int db = 0; db < 8; ++db) {
                    int vrow = db * 16 + l16;
                    int vpos = (ks * 4 + quad) ^ (l16 & 7);
                    bf16x8 vf = *(const bf16x8*)&Vt[cur][vrow * 128 + vpos * 16];
                    oaccA[db] = __builtin_amdgcn_mfma_f32_16x16x32_bf16(pfA[ks], vf, oaccA[db], 0, 0, 0);
                    oaccB[db] = __builtin_amdgcn_mfma_f32_16x16x32_bf16(pfB[ks], vf, oaccB[db], 0, 0, 0);
                }
        } else {
#pragma unroll
            for (int ks = 0; ks < 2; ++ks)
#pragma unroll
                for (int db = 0; db < 8; ++db) {
                    int vrow = db * 16 + l16;
                    int vpos = (ks * 4 + quad) ^ (l16 & 7);
                    bf16x8 vf = *(const bf16x8*)&Vt[cur][vrow * 128 + vpos * 16];
                    oaccB[db] = __builtin_amdgcn_mfma_f32_16x16x32_bf16(pfB[ks], vf, oaccB[db], 0, 0, 0);
                }
        }

        __syncthreads();   // all reads of buf cur done + prefetch DMA landed
    }

    // ---- epilogue: both tiles
    {
        float lr[4];
#pragma unroll
        for (int r = 0; r < 4; ++r)
            lr[r] = __shfl(liA, quad * 4 + r);
#pragma unroll
        for (int db = 0; db < 8; ++db)
#pragma unroll
            for (int r = 0; r < 4; ++r) {
                float v = oaccA[db][r] / lr[r];
                size_t row = (size_t)b * S_ + qrowA + quad * 4 + r;
                O[row * H_ + h * HD_ + db * 16 + l16] = __float2bfloat16(v);
            }
    }
    {
        float lr[4];
#pragma unroll
        for (int r = 0; r < 4; ++r)
            lr[r] = __shfl(liB, quad * 4 + r);
#pragma unroll
        for (int db = 0; db < 8; ++db)
#pragma unroll
            for (int r = 0; r < 4; ++r) {
                float v = oaccB[db][r] / lr[r];
                size_t row = (size_t)b * S_ + qrowB + quad * 4 + r;
                O[row * H_ + h * HD_ + db * 16 + l16] = __float2bfloat16(v);
            }
    }
}

// ---------------------------------------------------------------- launcher
extern "C" void kernel_launch(void* const* d_in, const int* in_sizes, int n_in,
                              void* d_out, int out_size, void* d_ws, size_t ws_size,
                              hipStream_t stream)
{
    const float* hs = (const float*)d_in[0];
    const float* Wq = (const float*)d_in[2];
    const float* bq = (const float*)d_in[3];
    const float* Wk = (const float*)d_in[4];
    const float* bk = (const float*)d_in[5];
    const float* Wv = (const float*)d_in[6];
    const float* bv = (const float*)d_in[7];
    const float* Wo = (const float*)d_in[8];
    const float* bo = (const float*)d_in[9];

    const size_t szX = (size_t)MTOT * H_;
    const size_t szW = (size_t)H_ * H_;

    __hip_bfloat16* Xbf = (__hip_bfloat16*)d_ws;   // reused as attention output
    __hip_bfloat16* Wqb = Xbf + szX;
    __hip_bfloat16* Wkb = Wqb + szW;
    __hip_bfloat16* Wvb = Wkb + szW;
    __hip_bfloat16* Wob = Wvb + szW;
    __hip_bfloat16* Qb  = Wob + szW;
    __hip_bfloat16* Kb  = Qb + szX;
    __hip_bfloat16* VTb = Kb + szX;                // V^T [(b*16+h)*128+d][s]

    castall<<<dim3(4096, 6), 256, 0, stream>>>(hs, Wq, Wk, Wv, Wo, Xbf, Wqb, Wkb, Wvb, Wob);

    gemm_qkv8<<<dim3(768), 512, 0, stream>>>(Xbf, Wqb, Wkb, Wvb, bq, bk, bv, Qb, Kb, VTb);

    attn_kernel<<<dim3(512), 256, 0, stream>>>(Qb, Kb, VTb, Xbf);

    gemm_out8<<<dim3(256), 512, 0, stream>>>(Xbf, Wob, bo, (float*)d_out);
}

// Round 12
// 360.457 us; speedup vs baseline: 1.1436x; 1.0310x over previous
//
#include <hip/hip_runtime.h>
#include <hip/hip_bf16.h>
#include <stdint.h>

#define B_   2
#define S_   2048
#define H_   2048
#define NH_  16
#define HD_  128
#define MTOT (B_*S_)   // 4096

typedef __attribute__((ext_vector_type(8))) short bf16x8;   // 8 bf16 = 4 VGPRs
typedef __attribute__((ext_vector_type(4))) short bf16x4;   // 8B packed store
typedef __attribute__((ext_vector_type(4))) float f32x4;    // MFMA C/D

__device__ __forceinline__ void gload_lds16(const void* g, void* l) {
    __builtin_amdgcn_global_load_lds(
        (const __attribute__((address_space(1))) void*)g,
        (__attribute__((address_space(3))) void*)l, 16, 0, 0);
}

__device__ __forceinline__ unsigned short f2bfu(float x) {
    __hip_bfloat16 h = __float2bfloat16(x);
    return *reinterpret_cast<unsigned short*>(&h);
}
__device__ __forceinline__ int packbf(float a, float b) {
    return (int)f2bfu(a) | ((int)f2bfu(b) << 16);
}

#define BAR()  asm volatile("s_barrier" ::: "memory")
#define WLG0() asm volatile("s_waitcnt lgkmcnt(0)" ::: "memory")
#define WVM(n) asm volatile("s_waitcnt vmcnt(" #n ")" ::: "memory")

// ---------------------------------------------------------------- fused fp32 -> bf16 casts
__global__ void castall(const float* __restrict__ hs,
                        const float* __restrict__ w0, const float* __restrict__ w1,
                        const float* __restrict__ w2, const float* __restrict__ w3,
                        __hip_bfloat16* __restrict__ xb,
                        __hip_bfloat16* __restrict__ o0, __hip_bfloat16* __restrict__ o1,
                        __hip_bfloat16* __restrict__ o2, __hip_bfloat16* __restrict__ o3)
{
    const size_t Q = 1048576;   // float4s per region
    const float* in; __hip_bfloat16* out; size_t base = 0;
    switch (blockIdx.y) {
        case 0:  in = hs; out = xb; break;
        case 1:  in = hs; out = xb; base = Q; break;
        case 2:  in = w0; out = o0; break;
        case 3:  in = w1; out = o1; break;
        case 4:  in = w2; out = o2; break;
        default: in = w3; out = o3; break;
    }
    size_t i = base + (size_t)blockIdx.x * 256 + threadIdx.x;
    float4 v = *(const float4*)(in + i * 4);
    uint2 o;
    o.x = (unsigned)packbf(v.x, v.y);
    o.y = (unsigned)packbf(v.z, v.w);
    *(uint2*)((char*)out + i * 8) = o;
}

// ---------------------------------------------------------------- shared helpers for 256x128 bodies
struct TileIdx {
    int tid, wave, lane, quad, l16, wr, wc, ro, co, bsub;
    int r0, c0, r1, c1;
    __device__ __forceinline__ TileIdx() {
        tid = threadIdx.x;
        wave = tid >> 6; lane = tid & 63;
        quad = lane >> 4; l16 = lane & 15;
        wr = wave >> 2; wc = wave & 3;
        ro = l16 * 64;
        co = (((l16 & 8) ? ((quad * 8) ^ 16) : (quad * 8)) << 1);
        bsub = (wc & 1) * 2;
        int D = tid * 16;
        int rg = D >> 11, cg = (D >> 10) & 1;
        int rr = (D >> 6) & 15, c = (D & 63) >> 1;
        int cs = (rr & 8) ? (c ^ 16) : c;
        r0 = rg * 16 + rr;  c0 = cg * 32 + cs;
        D = 8192 + tid * 16;
        rg = D >> 11; cg = (D >> 10) & 1;
        rr = (D >> 6) & 15; c = (D & 63) >> 1;
        cs = (rr & 8) ? (c ^ 16) : c;
        r1 = rg * 16 + rr;  c1 = cg * 32 + cs;
    }
};

// ---------------------------------------------------------------- 256x128 8-phase GEMM body
// Verified rounds 7-11: 39.8 us per 256-tile round, bank-conflict 0.
template<int EPI>   // 0 = fp32+bias, 2 = bf16 V^T scatter
__device__ __forceinline__ void gemm256x128_body(const __hip_bfloat16* __restrict__ Xp,
                                                 const __hip_bfloat16* __restrict__ Wp,
                                                 const float* __restrict__ bias,
                                                 void* __restrict__ Cout,
                                                 int bm, int bn, char* smem)
{
    TileIdx ix;

    char* const A0h = smem + ix.wr * 16384;
    char* const A1h = smem + 32768 + ix.wr * 16384;
    char* const B0h = smem + 65536 + (ix.wc >> 1) * 8192;
    char* const B1h = smem + 81920 + (ix.wc >> 1) * 8192;

    auto STG = [&](char* ldsb, const __hip_bfloat16* g) {
        gload_lds16(g + (size_t)ix.r0 * H_ + ix.c0, ldsb + ix.wave * 1024);
        gload_lds16(g + (size_t)ix.r1 * H_ + ix.c1, ldsb + 8192 + ix.wave * 1024);
    };
    auto STG1 = [&](char* ldsb, const __hip_bfloat16* g) {
        gload_lds16(g + (size_t)ix.r0 * H_ + ix.c0, ldsb + ix.wave * 1024);
    };
    auto SRCA = [&](const __hip_bfloat16* P, int t, int hf) {
        return P + (size_t)(hf * 128) * H_ + (size_t)t * 64;
    };
    auto SRCB = [&](const __hip_bfloat16* P, int t, int hf) {
        return P + (size_t)(hf * 64) * H_ + (size_t)t * 64;
    };

    f32x4 acc[8][2] = {};

    STG (smem,          SRCA(Xp, 0, 0));
    STG (smem + 16384,  SRCA(Xp, 0, 1));
    STG1(smem + 65536,        SRCB(Wp, 0, 0));
    STG1(smem + 65536 + 8192, SRCB(Wp, 0, 1));
    STG1(smem + 81920,        SRCB(Wp, 1, 0));
    STG1(smem + 81920 + 8192, SRCB(Wp, 1, 1));
    WVM(2);
    BAR();

    const int NIT = H_ / 128;  // 16 iterations, 2 K-tiles each
    bf16x8 bfr[2][2];
    for (int j = 0; j < NIT; ++j) {
        const bool more = (j < NIT - 1);
        const int t1 = 2 * j + 1;
#pragma unroll
        for (int ph = 0; ph < 8; ++ph) {
            const int p = ph & 3;
            char* aA = (ph < 4) ? A0h : A1h;
            char* aB = (ph < 4) ? B0h : B1h;

            if (p == 0) {
#pragma unroll
                for (int jj = 0; jj < 2; ++jj)
#pragma unroll
                    for (int kk = 0; kk < 2; ++kk)
                        bfr[jj][kk] = *(const bf16x8*)(aB + ((ix.bsub + jj) * 2 + kk) * 1024 + ix.ro + ix.co);
            }
            bf16x8 af[2][2];
#pragma unroll
            for (int i2 = 0; i2 < 2; ++i2)
#pragma unroll
                for (int kk = 0; kk < 2; ++kk)
                    af[i2][kk] = *(const bf16x8*)(aA + ((2 * p + i2) * 2 + kk) * 1024 + ix.ro + ix.co);

            if (ph == 0) { STG(smem + 32768, SRCA(Xp, t1, 0));
                           STG(smem + 49152, SRCA(Xp, t1, 1)); }
            else if (ph == 1 && more) STG1(smem + 65536,        SRCB(Wp, t1 + 1, 0));
            else if (ph == 2 && more) STG1(smem + 65536 + 8192, SRCB(Wp, t1 + 1, 1));
            else if (ph == 4 && more) STG (smem,                SRCA(Xp, t1 + 1, 0));
            else if (ph == 5 && more) STG (smem + 16384,        SRCA(Xp, t1 + 1, 1));
            else if (ph == 6 && more) STG1(smem + 81920,        SRCB(Wp, t1 + 2, 0));
            else if (ph == 7 && more) STG1(smem + 81920 + 8192, SRCB(Wp, t1 + 2, 1));

            if (ph == 3) { if (more) { WVM(2); } else { WVM(0); } }
            if (ph == 7 && more) { WVM(2); }

            BAR();
            WLG0();
            __builtin_amdgcn_sched_barrier(0);
            __builtin_amdgcn_s_setprio(1);
#pragma unroll
            for (int kk = 0; kk < 2; ++kk)
#pragma unroll
                for (int i2 = 0; i2 < 2; ++i2)
#pragma unroll
                    for (int jj = 0; jj < 2; ++jj)
                        acc[2 * p + i2][jj] = __builtin_amdgcn_mfma_f32_16x16x32_bf16(
                            af[i2][kk], bfr[jj][kk], acc[2 * p + i2][jj], 0, 0, 0);
            __builtin_amdgcn_s_setprio(0);
            BAR();
        }
    }

    if (EPI == 2) {
        __hip_bfloat16* VTo = (__hip_bfloat16*)Cout;
#pragma unroll
        for (int i = 0; i < 8; ++i) {
            int tok = bm * 256 + ix.wr * 128 + i * 16 + ix.quad * 4;
            int b = tok >> 11, s = tok & (S_ - 1);
#pragma unroll
            for (int jj = 0; jj < 2; ++jj) {
                int col = bn * 128 + (ix.wc >> 1) * 64 + (ix.wc & 1) * 32 + jj * 16 + ix.l16;
                int h = col >> 7, d = col & 127;
                float bv = bias[col];
                bf16x4 v;
#pragma unroll
                for (int r = 0; r < 4; ++r)
                    v[r] = (short)f2bfu(acc[i][jj][r] + bv);
                *(bf16x4*)(VTo + ((size_t)(b * 16 + h) * 128 + d) * S_ + s) = v;
            }
        }
    } else {
#pragma unroll
        for (int i = 0; i < 8; ++i) {
            int row = bm * 256 + ix.wr * 128 + i * 16 + ix.quad * 4;
#pragma unroll
            for (int jj = 0; jj < 2; ++jj) {
                int col = bn * 128 + (ix.wc >> 1) * 64 + (ix.wc & 1) * 32 + jj * 16 + ix.l16;
                float bv = bias[col];
#pragma unroll
                for (int r = 0; r < 4; ++r)
                    ((float*)Cout)[(size_t)(row + r) * H_ + col] = acc[i][jj][r] + bv;
            }
        }
    }
}

// ---------------------------------------------------------------- fused Q+K 256x128 body
// A-tile (X) shared by both outputs: stage A once, both W panels; 16 MFMA/phase (same
// barrier skeleton as verified body -> halves barrier cost per FLOP on Q/K portion).
// LDS 128K: A dbuf [0,64K) | Bq buf0 [64K,80K) buf1 [80K,96K) | Bk buf0 [96K,112K) buf1 [112K,128K).
// vmcnt audit (FIFO): B-slots carry 2 loads each -> WVM(4) at ph3/ph7 leaves exactly the
// newest B-pair (4 loads) outstanding; forces A(next) + B(current-read) landed. Prologue:
// 12 loads, WVM(4) leaves tile-1 B's. Last iter ph3 drains WVM(0).
__device__ __forceinline__ void gemm256x128_qk_body(const __hip_bfloat16* __restrict__ Xp,
                                                    const __hip_bfloat16* __restrict__ Wqp,
                                                    const __hip_bfloat16* __restrict__ Wkp,
                                                    const float* __restrict__ bq,
                                                    const float* __restrict__ bk,
                                                    __hip_bfloat16* __restrict__ Qo,
                                                    __hip_bfloat16* __restrict__ Ko,
                                                    int bm, int bn, char* smem)
{
    TileIdx ix;

    char* const A0h  = smem + ix.wr * 16384;
    char* const A1h  = smem + 32768 + ix.wr * 16384;
    char* const Bq0h = smem + 65536  + (ix.wc >> 1) * 8192;
    char* const Bq1h = smem + 81920  + (ix.wc >> 1) * 8192;
    char* const Bk0h = smem + 98304  + (ix.wc >> 1) * 8192;
    char* const Bk1h = smem + 114688 + (ix.wc >> 1) * 8192;

    auto STG = [&](char* ldsb, const __hip_bfloat16* g) {
        gload_lds16(g + (size_t)ix.r0 * H_ + ix.c0, ldsb + ix.wave * 1024);
        gload_lds16(g + (size_t)ix.r1 * H_ + ix.c1, ldsb + 8192 + ix.wave * 1024);
    };
    auto STG1 = [&](char* ldsb, const __hip_bfloat16* g) {
        gload_lds16(g + (size_t)ix.r0 * H_ + ix.c0, ldsb + ix.wave * 1024);
    };
    auto SRCA = [&](const __hip_bfloat16* P, int t, int hf) {
        return P + (size_t)(hf * 128) * H_ + (size_t)t * 64;
    };
    auto SRCB = [&](const __hip_bfloat16* P, int t, int hf) {
        return P + (size_t)(hf * 64) * H_ + (size_t)t * 64;
    };

    f32x4 accq[8][2] = {}, acck[8][2] = {};

    // prologue: A(0) 4 loads, B(0) 4 loads, B(1) 4 loads (issue order matters for WVM)
    STG (smem,                  SRCA(Xp, 0, 0));
    STG (smem + 16384,          SRCA(Xp, 0, 1));
    STG1(smem + 65536,          SRCB(Wqp, 0, 0));
    STG1(smem + 65536 + 8192,   SRCB(Wqp, 0, 1));
    STG1(smem + 98304,          SRCB(Wkp, 0, 0));
    STG1(smem + 98304 + 8192,   SRCB(Wkp, 0, 1));
    STG1(smem + 81920,          SRCB(Wqp, 1, 0));
    STG1(smem + 81920 + 8192,   SRCB(Wqp, 1, 1));
    STG1(smem + 114688,         SRCB(Wkp, 1, 0));
    STG1(smem + 114688 + 8192,  SRCB(Wkp, 1, 1));
    WVM(4);                     // A(0)+B(0) landed; B(1)'s 4 loads in flight
    BAR();

    const int NIT = H_ / 128;
    bf16x8 bfq[2][2], bfk[2][2];
    for (int j = 0; j < NIT; ++j) {
        const bool more = (j < NIT - 1);
        const int t1 = 2 * j + 1;
#pragma unroll
        for (int ph = 0; ph < 8; ++ph) {
            const int p = ph & 3;
            char* aA  = (ph < 4) ? A0h  : A1h;
            char* aBq = (ph < 4) ? Bq0h : Bq1h;
            char* aBk = (ph < 4) ? Bk0h : Bk1h;

            if (p == 0) {
#pragma unroll
                for (int jj = 0; jj < 2; ++jj)
#pragma unroll
                    for (int kk = 0; kk < 2; ++kk) {
                        bfq[jj][kk] = *(const bf16x8*)(aBq + ((ix.bsub + jj) * 2 + kk) * 1024 + ix.ro + ix.co);
                        bfk[jj][kk] = *(const bf16x8*)(aBk + ((ix.bsub + jj) * 2 + kk) * 1024 + ix.ro + ix.co);
                    }
            }
            bf16x8 af[2][2];
#pragma unroll
            for (int i2 = 0; i2 < 2; ++i2)
#pragma unroll
                for (int kk = 0; kk < 2; ++kk)
                    af[i2][kk] = *(const bf16x8*)(aA + ((2 * p + i2) * 2 + kk) * 1024 + ix.ro + ix.co);

            // stage map: ph0 A(2j+1)->buf1A; ph1 Bq(2j+2), ph2 Bk(2j+2) -> buf0;
            //            ph4/5 A(2j+2)->buf0A; ph6 Bq(2j+3), ph7 Bk(2j+3) -> buf1
            if (ph == 0) { STG(smem + 32768, SRCA(Xp, t1, 0));
                           STG(smem + 49152, SRCA(Xp, t1, 1)); }
            else if (ph == 1 && more) { STG1(smem + 65536,         SRCB(Wqp, t1 + 1, 0));
                                        STG1(smem + 65536 + 8192,  SRCB(Wqp, t1 + 1, 1)); }
            else if (ph == 2 && more) { STG1(smem + 98304,         SRCB(Wkp, t1 + 1, 0));
                                        STG1(smem + 98304 + 8192,  SRCB(Wkp, t1 + 1, 1)); }
            else if (ph == 4 && more) STG(smem,          SRCA(Xp, t1 + 1, 0));
            else if (ph == 5 && more) STG(smem + 16384,  SRCA(Xp, t1 + 1, 1));
            else if (ph == 6 && more) { STG1(smem + 81920,         SRCB(Wqp, t1 + 2, 0));
                                        STG1(smem + 81920 + 8192,  SRCB(Wqp, t1 + 2, 1)); }
            else if (ph == 7 && more) { STG1(smem + 114688,        SRCB(Wkp, t1 + 2, 0));
                                        STG1(smem + 114688 + 8192, SRCB(Wkp, t1 + 2, 1)); }

            if (ph == 3) { if (more) { WVM(4); } else { WVM(0); } }
            if (ph == 7 && more) { WVM(4); }

            BAR();
            WLG0();
            __builtin_amdgcn_sched_barrier(0);
            __builtin_amdgcn_s_setprio(1);
#pragma unroll
            for (int kk = 0; kk < 2; ++kk)
#pragma unroll
                for (int i2 = 0; i2 < 2; ++i2)
#pragma unroll
                    for (int jj = 0; jj < 2; ++jj) {
                        accq[2 * p + i2][jj] = __builtin_amdgcn_mfma_f32_16x16x32_bf16(
                            af[i2][kk], bfq[jj][kk], accq[2 * p + i2][jj], 0, 0, 0);
                        acck[2 * p + i2][jj] = __builtin_amdgcn_mfma_f32_16x16x32_bf16(
                            af[i2][kk], bfk[jj][kk], acck[2 * p + i2][jj], 0, 0, 0);
                    }
            __builtin_amdgcn_s_setprio(0);
            BAR();
        }
    }

    // epilogue: Q then K, bf16 row-major + bias
#pragma unroll
    for (int i = 0; i < 8; ++i) {
        int row = bm * 256 + ix.wr * 128 + i * 16 + ix.quad * 4;
#pragma unroll
        for (int jj = 0; jj < 2; ++jj) {
            int col = bn * 128 + (ix.wc >> 1) * 64 + (ix.wc & 1) * 32 + jj * 16 + ix.l16;
            float bvq = bq[col], bvk = bk[col];
#pragma unroll
            for (int r = 0; r < 4; ++r) {
                Qo[(size_t)(row + r) * H_ + col] = __float2bfloat16(accq[i][jj][r] + bvq);
                Ko[(size_t)(row + r) * H_ + col] = __float2bfloat16(acck[i][jj][r] + bvk);
            }
        }
    }
}

// fused QKV: 512 blocks = 2 exact rounds. bids 0-255: Q+K fused (16 MFMA/phase);
// bids 256-511: V (verified body). bn-fastest bijective swizzle within each half.
__global__ __launch_bounds__(512, 2)
void gemm_qkvf(const __hip_bfloat16* __restrict__ X,
               const __hip_bfloat16* __restrict__ Wq, const __hip_bfloat16* __restrict__ Wk,
               const __hip_bfloat16* __restrict__ Wv,
               const float* __restrict__ bq, const float* __restrict__ bk,
               const float* __restrict__ bv,
               __hip_bfloat16* __restrict__ Qo, __hip_bfloat16* __restrict__ Ko,
               __hip_bfloat16* __restrict__ VTo)
{
    __shared__ __align__(16) char smem[131072];

    const int bid = blockIdx.x;
    if (bid < 256) {
        const int swz = (bid & 7) * 32 + (bid >> 3);   // bijective (256 % 8 == 0)
        const int bn  = swz & 15;
        const int bm  = swz >> 4;
        gemm256x128_qk_body(X + (size_t)(bm * 256) * H_,
                            Wq + (size_t)(bn * 128) * H_, Wk + (size_t)(bn * 128) * H_,
                            bq, bk, Qo, Ko, bm, bn, smem);
    } else {
        const int b2  = bid - 256;
        const int swz = (b2 & 7) * 32 + (b2 >> 3);
        const int bn  = swz & 15;
        const int bm  = swz >> 4;
        gemm256x128_body<2>(X + (size_t)(bm * 256) * H_, Wv + (size_t)(bn * 128) * H_,
                            bv, VTo, bm, bn, smem);
    }
}

// O-projection: 256 tiles = one full round (verified round 11: ~43-50 us)
__global__ __launch_bounds__(512, 2)
void gemm_out8(const __hip_bfloat16* __restrict__ A, const __hip_bfloat16* __restrict__ W,
               const float* __restrict__ bias, float* __restrict__ C)
{
    __shared__ __align__(16) char smem[98304];
    const int bid = blockIdx.x;                  // 0..255
    const int swz = (bid & 7) * 32 + (bid >> 3); // bijective (256 % 8 == 0)
    const int bn  = swz & 15;
    const int bm  = swz >> 4;
    gemm256x128_body<0>(A + (size_t)(bm * 256) * H_, W + (size_t)(bn * 128) * H_,
                        bias, C, bm, bn, smem);
}

// ---------------------------------------------------------------- flash attention v9: q-pair blocks
// (verified round 10: 512 blocks, depth-paired load balance, K/V-shared 2-tile MFMAs)
__global__ __launch_bounds__(256, 2)
void attn_kernel(const __hip_bfloat16* __restrict__ Q,
                 const __hip_bfloat16* __restrict__ K,
                 const __hip_bfloat16* __restrict__ VT,   // [(b*16+h)*128 + d][s]
                 __hip_bfloat16* __restrict__ O)
{
    __shared__ __align__(16) char Ks[2][16384];   // K-tile: 64 key-rows x 256B
    __shared__ __align__(16) char Vt[2][16384];   // V^T-tile: 128 d-rows x 128B

    const int tid  = threadIdx.x;
    const int wave = tid >> 6, lane = tid & 63;
    const int quad = lane >> 4, l16 = lane & 15;

    const int lid = blockIdx.x;                  // 0..511
    const int xcd = lid & 7;
    const int q   = lid >> 3;                    // 0..63
    const int grp = q >> 4;                      // 0..3
    const int k15 = q & 15;
    const int bh  = (grp << 3) | xcd;            // 0..31
    const int u   = (grp < 2) ? (15 - k15) : k15;   // complementary across rounds
    const int b   = bh >> 4, h = bh & 15;
    const int qbA = 2 * u, qbB = 2 * u + 1;

    const size_t headoff = (size_t)b * S_ * H_ + (size_t)h * HD_;
    const __hip_bfloat16* Qp  = Q + headoff;
    const __hip_bfloat16* Kp  = K + headoff;
    const __hip_bfloat16* Vtp = VT + (size_t)(b * 16 + h) * 128 * S_;

    const float scale  = 0.08838834764831843f;    // 1/sqrt(128)
    const float THRraw = 90.50966799187809f;      // 8 / scale
    const int A0 = (((quad & 1) * 2) * 16 + l16) * 4;
    const int A1 = A0 + 64;
    const bool hiq = (quad >= 2);

    const int qrow_local = wave * 16;
    const int qrowA = qbA * 64 + qrow_local;
    const int qrowB = qbB * 64 + qrow_local;

    bf16x8 qfA[4], qfB[4];
#pragma unroll
    for (int kd = 0; kd < 4; ++kd) {
        qfA[kd] = *(const bf16x8*)(Qp + (size_t)(qrowA + l16) * H_ + kd * 32 + quad * 8);
        qfB[kd] = *(const bf16x8*)(Qp + (size_t)(qrowB + l16) * H_ + kd * 32 + quad * 8);
    }

    f32x4 oaccA[8] = {}, oaccB[8] = {};
    float miA = -1e30f, liA = 0.0f;
    float miB = -1e30f, liB = 0.0f;

    auto sm_xform = [&](f32x4 (&sacc)[4], float& mi, float& li, f32x4 (&oacc)[8],
                        bool diag, bf16x8 (&pf)[2]) {
        float p[4][4];
        float tm = -1e30f;
#pragma unroll
        for (int cb = 0; cb < 4; ++cb)
#pragma unroll
            for (int r = 0; r < 4; ++r) {
                float s = sacc[cb][r];           // RAW; scale folded into exp
                if (diag) {
                    int keyl = cb * 16 + quad * 4 + r;
                    if (keyl > qrow_local + l16) s = -1e30f;
                }
                p[cb][r] = s;
                tm = fmaxf(tm, s);
            }
        tm = fmaxf(tm, __shfl_xor(tm, 16));
        tm = fmaxf(tm, __shfl_xor(tm, 32));

        const bool noresc = __all(tm - mi <= THRraw);
        float mnew = noresc ? mi : fmaxf(mi, tm);
        float ms = mnew * scale;

        float sum = 0.0f;
#pragma unroll
        for (int cb = 0; cb < 4; ++cb)
#pragma unroll
            for (int r = 0; r < 4; ++r) {
                float e = __expf(__builtin_fmaf(p[cb][r], scale, -ms));
                p[cb][r] = e;
                sum += e;
            }
        sum += __shfl_xor(sum, 16);
        sum += __shfl_xor(sum, 32);

        if (noresc) {
            li = li + sum;
        } else {
            float alpha = __expf((mi - mnew) * scale);
            li = li * alpha + sum;
            float ar[4];
#pragma unroll
            for (int r = 0; r < 4; ++r)
                ar[r] = __shfl(alpha, quad * 4 + r);
#pragma unroll
            for (int db = 0; db < 8; ++db)
#pragma unroll
                for (int r = 0; r < 4; ++r)
                    oacc[db][r] *= ar[r];
        }
        mi = mnew;

        int Pp[4][2];
#pragma unroll
        for (int cb = 0; cb < 4; ++cb) {
            Pp[cb][0] = packbf(p[cb][0], p[cb][1]);
            Pp[cb][1] = packbf(p[cb][2], p[cb][3]);
        }
#pragma unroll
        for (int ks = 0; ks < 2; ++ks) {
            int c0 = 2 * ks, c1 = 2 * ks + 1;
            int d0 = __builtin_amdgcn_ds_bpermute(A0, Pp[c0][0]);
            int e0 = __builtin_amdgcn_ds_bpermute(A0, Pp[c1][0]);
            int d1 = __builtin_amdgcn_ds_bpermute(A0, Pp[c0][1]);
            int e1 = __builtin_amdgcn_ds_bpermute(A0, Pp[c1][1]);
            int d2 = __builtin_amdgcn_ds_bpermute(A1, Pp[c0][0]);
            int e2 = __builtin_amdgcn_ds_bpermute(A1, Pp[c1][0]);
            int d3 = __builtin_amdgcn_ds_bpermute(A1, Pp[c0][1]);
            int e3 = __builtin_amdgcn_ds_bpermute(A1, Pp[c1][1]);
            union { int i[4]; bf16x8 v; } w;
            w.i[0] = hiq ? e0 : d0;
            w.i[1] = hiq ? e1 : d1;
            w.i[2] = hiq ? e2 : d2;
            w.i[3] = hiq ? e3 : d3;
            pf[ks] = w.v;
        }
    };

    // prologue: tile 0 -> buf 0
#pragma unroll
    for (int t = 0; t < 4; ++t) {
        int c = wave * 256 + t * 64 + lane;
        int krow = c >> 4, kpos = c & 15;
        gload_lds16(Kp + (size_t)krow * H_ + (kpos ^ (krow & 7)) * 8,
                    &Ks[0][(wave * 256 + t * 64) * 16]);
        int vrow = c >> 3, vpos = c & 7;
        gload_lds16(Vtp + (size_t)vrow * S_ + (vpos ^ (vrow & 7)) * 8,
                    &Vt[0][(wave * 256 + t * 64) * 16]);
    }
    __syncthreads();

    for (int kb = 0; kb <= qbB; ++kb) {
        const int cur = kb & 1;
        const bool more   = (kb < qbB);
        const bool aliveA = (kb <= qbA);         // block-uniform

        if (more) {
            const __hip_bfloat16* Kn = Kp + (size_t)(kb + 1) * 64 * H_;
            const int vcol = (kb + 1) * 64;
#pragma unroll
            for (int t = 0; t < 4; ++t) {
                int c = wave * 256 + t * 64 + lane;
                int krow = c >> 4, kpos = c & 15;
                gload_lds16(Kn + (size_t)krow * H_ + (kpos ^ (krow & 7)) * 8,
                            &Ks[cur ^ 1][(wave * 256 + t * 64) * 16]);
                int vrow = c >> 3, vpos = c & 7;
                gload_lds16(Vtp + (size_t)vrow * S_ + vcol + (vpos ^ (vrow & 7)) * 8,
                            &Vt[cur ^ 1][(wave * 256 + t * 64) * 16]);
            }
        }

        f32x4 saccA[4] = {}, saccB[4] = {};
#pragma unroll
        for (int cb = 0; cb < 4; ++cb) {
#pragma unroll
            for (int kd = 0; kd < 4; ++kd) {
                int row = cb * 16 + l16;
                int pos = (4 * kd + quad) ^ (l16 & 7);
                bf16x8 kf = *(const bf16x8*)&Ks[cur][row * 256 + pos * 16];
                saccA[cb] = __builtin_amdgcn_mfma_f32_16x16x32_bf16(kf, qfA[kd], saccA[cb], 0, 0, 0);
                saccB[cb] = __builtin_amdgcn_mfma_f32_16x16x32_bf16(kf, qfB[kd], saccB[cb], 0, 0, 0);
            }
        }

        bf16x8 pfA[2], pfB[2];
        if (aliveA) sm_xform(saccA, miA, liA, oaccA, kb == qbA, pfA);
        sm_xform(saccB, miB, liB, oaccB, kb == qbB, pfB);

        if (aliveA) {
#pragma unroll
            for (int ks = 0; ks < 2; ++ks)
#pragma unroll
                for (int db = 0; db < 8; ++db) {
                    int vrow = db * 16 + l16;
                    int vpos = (ks * 4 + quad) ^ (l16 & 7);
                    bf16x8 vf = *(const bf16x8*)&Vt[cur][vrow * 128 + vpos * 16];
                    oaccA[db] = __builtin_amdgcn_mfma_f32_16x16x32_bf16(pfA[ks], vf, oaccA[db], 0, 0, 0);
                    oaccB[db] = __builtin_amdgcn_mfma_f32_16x16x32_bf16(pfB[ks], vf, oaccB[db], 0, 0, 0);
                }
        } else {
#pragma unroll
            for (int ks = 0; ks < 2; ++ks)
#pragma unroll
                for (int db = 0; db < 8; ++db) {
                    int vrow = db * 16 + l16;
                    int vpos = (ks * 4 + quad) ^ (l16 & 7);
                    bf16x8 vf = *(const bf16x8*)&Vt[cur][vrow * 128 + vpos * 16];
                    oaccB[db] = __builtin_amdgcn_mfma_f32_16x16x32_bf16(pfB[ks], vf, oaccB[db], 0, 0, 0);
                }
        }

        __syncthreads();   // all reads of buf cur done + prefetch DMA landed
    }

    // ---- epilogue: both tiles
    {
        float lr[4];
#pragma unroll
        for (int r = 0; r < 4; ++r)
            lr[r] = __shfl(liA, quad * 4 + r);
#pragma unroll
        for (int db = 0; db < 8; ++db)
#pragma unroll
            for (int r = 0; r < 4; ++r) {
                float v = oaccA[db][r] / lr[r];
                size_t row = (size_t)b * S_ + qrowA + quad * 4 + r;
                O[row * H_ + h * HD_ + db * 16 + l16] = __float2bfloat16(v);
            }
    }
    {
        float lr[4];
#pragma unroll
        for (int r = 0; r < 4; ++r)
            lr[r] = __shfl(liB, quad * 4 + r);
#pragma unroll
        for (int db = 0; db < 8; ++db)
#pragma unroll
            for (int r = 0; r < 4; ++r) {
                float v = oaccB[db][r] / lr[r];
                size_t row = (size_t)b * S_ + qrowB + quad * 4 + r;
                O[row * H_ + h * HD_ + db * 16 + l16] = __float2bfloat16(v);
            }
    }
}

// ---------------------------------------------------------------- launcher
extern "C" void kernel_launch(void* const* d_in, const int* in_sizes, int n_in,
                              void* d_out, int out_size, void* d_ws, size_t ws_size,
                              hipStream_t stream)
{
    const float* hs = (const float*)d_in[0];
    const float* Wq = (const float*)d_in[2];
    const float* bq = (const float*)d_in[3];
    const float* Wk = (const float*)d_in[4];
    const float* bk = (const float*)d_in[5];
    const float* Wv = (const float*)d_in[6];
    const float* bv = (const float*)d_in[7];
    const float* Wo = (const float*)d_in[8];
    const float* bo = (const float*)d_in[9];

    const size_t szX = (size_t)MTOT * H_;
    const size_t szW = (size_t)H_ * H_;

    __hip_bfloat16* Xbf = (__hip_bfloat16*)d_ws;   // reused as attention output
    __hip_bfloat16* Wqb = Xbf + szX;
    __hip_bfloat16* Wkb = Wqb + szW;
    __hip_bfloat16* Wvb = Wkb + szW;
    __hip_bfloat16* Wob = Wvb + szW;
    __hip_bfloat16* Qb  = Wob + szW;
    __hip_bfloat16* Kb  = Qb + szX;
    __hip_bfloat16* VTb = Kb + szX;                // V^T [(b*16+h)*128+d][s]

    castall<<<dim3(4096, 6), 256, 0, stream>>>(hs, Wq, Wk, Wv, Wo, Xbf, Wqb, Wkb, Wvb, Wob);

    gemm_qkvf<<<dim3(512), 512, 0, stream>>>(Xbf, Wqb, Wkb, Wvb, bq, bk, bv, Qb, Kb, VTb);

    attn_kernel<<<dim3(512), 256, 0, stream>>>(Qb, Kb, VTb, Xbf);

    gemm_out8<<<dim3(256), 512, 0, stream>>>(Xbf, Wob, bo, (float*)d_out);
}